// Round 1
// 1575.329 us; speedup vs baseline: 1.0462x; 1.0462x over previous
//
#include <hip/hip_runtime.h>
#include <cstdint>

typedef unsigned short u16;
typedef short bf16x8 __attribute__((ext_vector_type(8)));
typedef float f32x4 __attribute__((ext_vector_type(4)));

#define PLD 18688   // proj leading dim (q2048 | k128 | v128 | ff8192 | gate8192)
#define ALD 10240   // amat leading dim ([attn 2048 | ffh 8192])
#define LOG2E 1.4426950408889634f
#define QSCALE 0.08838834764831845f   // 128^-0.5
#define RMS_SCALE 45.25483399593904f  // 2048^0.5

__device__ __forceinline__ u16 f2bf(float f) {
  union { float f; unsigned int u; } v; v.f = f;
  unsigned int u = v.u;
  return (u16)((u + 0x7fffu + ((u >> 16) & 1u)) >> 16);
}
__device__ __forceinline__ float bf2f(u16 h) {
  union { unsigned int u; float f; } v; v.u = ((unsigned int)h) << 16;
  return v.f;
}

__device__ __forceinline__ void gload_lds16(const void* g, void* l) {
  __builtin_amdgcn_global_load_lds((__attribute__((address_space(1))) void*)(g),
                                   (__attribute__((address_space(3))) void*)(l),
                                   16, 0, 0);
}

// ---------------- RMSNorm: x f32 [4096,2048] -> xn bf16 ----------------
__global__ __launch_bounds__(256) void rmsnorm_kernel(const float* __restrict__ x,
                                                      const float* __restrict__ gamma,
                                                      u16* __restrict__ xn) {
  const int row = blockIdx.x;
  const int tid = threadIdx.x;
  const float4* xr = (const float4*)(x + (size_t)row * 2048);
  float4 v0 = xr[tid], v1 = xr[tid + 256];
  float s = v0.x*v0.x + v0.y*v0.y + v0.z*v0.z + v0.w*v0.w
          + v1.x*v1.x + v1.y*v1.y + v1.z*v1.z + v1.w*v1.w;
  for (int m = 1; m < 64; m <<= 1) s += __shfl_xor(s, m, 64);
  __shared__ float red[4];
  if ((tid & 63) == 0) red[tid >> 6] = s;
  __syncthreads();
  float tot = red[0] + red[1] + red[2] + red[3];
  float inv = rsqrtf(tot + 1e-5f) * RMS_SCALE;
  const float4* gp = (const float4*)gamma;
  float4 g0 = gp[tid], g1 = gp[tid + 256];
  u16* xo = xn + (size_t)row * 2048;
  union { u16 h[4]; uint2 u; } o0, o1;
  o0.h[0] = f2bf(v0.x*inv*g0.x); o0.h[1] = f2bf(v0.y*inv*g0.y);
  o0.h[2] = f2bf(v0.z*inv*g0.z); o0.h[3] = f2bf(v0.w*inv*g0.w);
  o1.h[0] = f2bf(v1.x*inv*g1.x); o1.h[1] = f2bf(v1.y*inv*g1.y);
  o1.h[2] = f2bf(v1.z*inv*g1.z); o1.h[3] = f2bf(v1.w*inv*g1.w);
  *(uint2*)(xo + tid*4) = o0.u;
  *(uint2*)(xo + (tid+256)*4) = o1.u;
}

// ------- transpose+convert: src f32 [K,N] -> dst bf16 [N, dstride] at col doff -------
__global__ __launch_bounds__(256) void tconv(const float* __restrict__ src,
                                             u16* __restrict__ dst,
                                             int K, int N, int dstride, int doff) {
  __shared__ u16 t[32][33];
  const int tx = threadIdx.x & 31, ty = threadIdx.x >> 5;
  const int n0 = blockIdx.x * 32, k0 = blockIdx.y * 32;
  #pragma unroll
  for (int yy = 0; yy < 4; yy++) {
    int r = ty + yy*8;
    t[r][tx] = f2bf(src[(size_t)(k0 + r) * N + n0 + tx]);
  }
  __syncthreads();
  #pragma unroll
  for (int yy = 0; yy < 4; yy++) {
    int r = ty + yy*8;
    dst[(size_t)(n0 + r) * dstride + doff + k0 + tx] = t[tx][r];
  }
}

// ---------------- GEMM (m97 128^2 recipe) — kept for GEMM-2 ----------------
template <int OUT_BF16, int GC>
__global__ __launch_bounds__(256) void gemm_bt(const u16* __restrict__ A,
                                               const u16* __restrict__ Bt,
                                               void* __restrict__ Cv,
                                               int M, int N, int K) {
  __shared__ alignas(16) u16 sA[128*32];
  __shared__ alignas(16) u16 sB[128*32];
  const int numRow = M >> 7;
  const int per = GC * numRow;
  const int pid = blockIdx.x;
  const int g = pid / per, inner = pid % per;
  const int colT = g * GC + inner / numRow;
  const int rowT = inner % numRow;
  const int row0 = rowT * 128, col0 = colT * 128;

  const int tid = threadIdx.x;
  const int w = tid >> 6, lane = tid & 63, quad = lane >> 4, l16 = lane & 15;
  const int wr = (w >> 1) * 64, wc = (w & 1) * 64;
  const f32x4 zero = {0.f, 0.f, 0.f, 0.f};
  f32x4 acc[4][4];
  #pragma unroll
  for (int mi = 0; mi < 4; mi++)
    #pragma unroll
    for (int ni = 0; ni < 4; ni++) acc[mi][ni] = zero;

  for (int k0 = 0; k0 < K; k0 += 32) {
    __syncthreads();
    #pragma unroll
    for (int i = 0; i < 2; i++) {
      const int segbase = (i*4 + w) * 64;
      const int seg = segbase + lane;
      const int r = seg >> 2, c = (seg & 3) * 8;
      gload_lds16(A  + (size_t)(row0 + r) * K + k0 + c, sA + segbase * 8);
      gload_lds16(Bt + (size_t)(col0 + r) * K + k0 + c, sB + segbase * 8);
    }
    __syncthreads();
    bf16x8 af[4], bfr[4];
    #pragma unroll
    for (int mi = 0; mi < 4; mi++)
      af[mi] = *(const bf16x8*)&sA[(wr + mi*16 + l16)*32 + quad*8];
    #pragma unroll
    for (int ni = 0; ni < 4; ni++)
      bfr[ni] = *(const bf16x8*)&sB[(wc + ni*16 + l16)*32 + quad*8];
    #pragma unroll
    for (int mi = 0; mi < 4; mi++)
      #pragma unroll
      for (int ni = 0; ni < 4; ni++)
        acc[mi][ni] = __builtin_amdgcn_mfma_f32_16x16x32_bf16(af[mi], bfr[ni], acc[mi][ni], 0, 0, 0);
  }

  #pragma unroll
  for (int mi = 0; mi < 4; mi++) {
    const int rb = row0 + wr + mi*16 + quad*4;
    #pragma unroll
    for (int ni = 0; ni < 4; ni++) {
      const int cb = col0 + wc + ni*16 + l16;
      #pragma unroll
      for (int r = 0; r < 4; r++) {
        if (OUT_BF16) ((u16*)Cv)[(size_t)(rb + r) * N + cb] = f2bf(acc[mi][ni][r]);
        else          ((float*)Cv)[(size_t)(rb + r) * N + cb] = acc[mi][ni][r];
      }
    }
  }
}

// ---------------- GEMM 256^2 / BK=64 / 8-wave / 8-phase counted-vmcnt ----------------
// LDS layout (u16 elements): A at [0, 32768), B at [32768, 65536).
//   block(buf,ks,idx16) base = buf*16384 + ks*8192 + idx16*512   (1024B blocks)
//   within block: chunk l (16B) holds row (idx16*16 + (l&15)), k-cols (ks*32 + (l>>4)*8 .. +8)
//   -> ds_read_b128 at base + lane*8 is 1024B contiguous per wave (conflict-free),
//      and global_load_lds's linear lane ordering matches via per-lane source addrs.
// Schedule per K-tile t (buf bb=t&1): 4 phases (ks x ni-half), 16 MFMA each.
//   issues: ph0: A-ks1(t+1)->nb   ph1: B-ks1(t+1)->nb   ph2: A-ks0(t+2)->bb   ph3: B-ks0(t+2)->bb
//   (ks0 region of bb is dead after ph1, so t+2's ks0 can land in it at ph2.)
//   waits: vmcnt(8) end of ph1 (covers A/B-ks1(t)) and end of ph3 (covers A/B-ks0(t+1)).
#define BAR() do { asm volatile("" ::: "memory"); __builtin_amdgcn_s_barrier(); asm volatile("" ::: "memory"); } while (0)
#define WAITV(N) asm volatile("s_waitcnt vmcnt(" #N ")" ::: "memory")

template <int OUT_BF16>
__global__ __launch_bounds__(512, 2) void gemm256(const u16* __restrict__ A,
                                                  const u16* __restrict__ Bt,
                                                  void* __restrict__ Cv,
                                                  int M, int N, int K) {
  __shared__ alignas(16) u16 lds[65536];   // 128 KiB
  u16* const sB = lds + 32768;

  const int numRow = M >> 8;
  int pid = blockIdx.x;
  {  // bijective XCD swizzle (m204 form)
    const int nwg = gridDim.x;
    const int q = nwg >> 3, r = nwg & 7;
    const int xcd = pid & 7, lid = pid >> 3;
    pid = (xcd < r ? xcd * (q + 1) : r * (q + 1) + (xcd - r) * q) + lid;
  }
  const int colT = pid / numRow, rowT = pid % numRow;
  const int row0 = rowT << 8, col0 = colT << 8;

  const int tid = threadIdx.x;
  const int w = tid >> 6, lane = tid & 63, quad = lane >> 4, l16 = lane & 15;
  const int wr = w >> 2, wc = w & 3;           // 2 x 4 wave grid; wave owns 128x64 of C

  // per-lane pre-permuted global sources (16B chunks: 16 rows x 4 quads per block)
  const u16* aG  = A  + (size_t)(row0 + w * 16 + l16) * K + quad * 8;
  const u16* aG2 = aG + (size_t)128 * K;
  const u16* bG  = Bt + (size_t)(col0 + w * 16 + l16) * K + quad * 8;
  const u16* bG2 = bG + (size_t)128 * K;

  #define STAGE_A(bb, ks, kt) do { \
    gload_lds16(aG  + (kt) + (ks) * 32, lds + (bb) * 16384 + (ks) * 8192 + w * 512); \
    gload_lds16(aG2 + (kt) + (ks) * 32, lds + (bb) * 16384 + (ks) * 8192 + (8 + w) * 512); \
  } while (0)
  #define STAGE_B(bb, ks, kt) do { \
    gload_lds16(bG  + (kt) + (ks) * 32, sB + (bb) * 16384 + (ks) * 8192 + w * 512); \
    gload_lds16(bG2 + (kt) + (ks) * 32, sB + (bb) * 16384 + (ks) * 8192 + (8 + w) * 512); \
  } while (0)

  const f32x4 zero = {0.f, 0.f, 0.f, 0.f};
  f32x4 acc[8][4];
  #pragma unroll
  for (int mi = 0; mi < 8; mi++)
    #pragma unroll
    for (int ni = 0; ni < 4; ni++) acc[mi][ni] = zero;

  const int nt = K >> 6;
  // prologue: tile0 (4 units) + tile1 ks0 (2 units) = 12 loads/thread in flight
  STAGE_A(0, 0, 0);  STAGE_B(0, 0, 0);
  STAGE_A(0, 1, 0);  STAGE_B(0, 1, 0);
  STAGE_A(1, 0, 64); STAGE_B(1, 0, 64);
  WAITV(8);                      // retire A-ks0(0), B-ks0(0)
  BAR();

  const int aBase = wr * 8 * 512 + lane * 8;   // + buf*16384 + ks*8192 + mi*512
  const int bBase = wc * 4 * 512 + lane * 8;   // + buf*16384 + ks*8192 + ni*512

  for (int t = 0; t < nt; ++t) {
    const int bb = t & 1, nb = bb ^ 1;
    const int kt1 = (t + 1) << 6, kt2 = (t + 2) << 6;
    bf16x8 af[8], bf0, bf1;

    // ---- phase 0: ks=0, ni={0,1} ----
    #pragma unroll
    for (int mi = 0; mi < 8; mi++)
      af[mi] = *(const bf16x8*)(lds + bb * 16384 + aBase + mi * 512);
    bf0 = *(const bf16x8*)(sB + bb * 16384 + bBase);
    bf1 = *(const bf16x8*)(sB + bb * 16384 + bBase + 512);
    if (t + 1 < nt) STAGE_A(nb, 1, kt1);
    BAR();
    __builtin_amdgcn_s_setprio(1);
    #pragma unroll
    for (int mi = 0; mi < 8; mi++) {
      acc[mi][0] = __builtin_amdgcn_mfma_f32_16x16x32_bf16(af[mi], bf0, acc[mi][0], 0, 0, 0);
      acc[mi][1] = __builtin_amdgcn_mfma_f32_16x16x32_bf16(af[mi], bf1, acc[mi][1], 0, 0, 0);
    }
    __builtin_amdgcn_s_setprio(0);
    BAR();

    // ---- phase 1: ks=0, ni={2,3} ----
    bf0 = *(const bf16x8*)(sB + bb * 16384 + bBase + 1024);
    bf1 = *(const bf16x8*)(sB + bb * 16384 + bBase + 1536);
    if (t + 1 < nt) STAGE_B(nb, 1, kt1);
    BAR();
    __builtin_amdgcn_s_setprio(1);
    #pragma unroll
    for (int mi = 0; mi < 8; mi++) {
      acc[mi][2] = __builtin_amdgcn_mfma_f32_16x16x32_bf16(af[mi], bf0, acc[mi][2], 0, 0, 0);
      acc[mi][3] = __builtin_amdgcn_mfma_f32_16x16x32_bf16(af[mi], bf1, acc[mi][3], 0, 0, 0);
    }
    __builtin_amdgcn_s_setprio(0);
    if (t + 1 < nt) { WAITV(8); } else { WAITV(0); }   // retire A/B-ks1(t)
    BAR();

    // ---- phase 2: ks=1, ni={0,1} ----
    #pragma unroll
    for (int mi = 0; mi < 8; mi++)
      af[mi] = *(const bf16x8*)(lds + bb * 16384 + 8192 + aBase + mi * 512);
    bf0 = *(const bf16x8*)(sB + bb * 16384 + 8192 + bBase);
    bf1 = *(const bf16x8*)(sB + bb * 16384 + 8192 + bBase + 512);
    if (t + 2 < nt) STAGE_A(bb, 0, kt2);
    BAR();
    __builtin_amdgcn_s_setprio(1);
    #pragma unroll
    for (int mi = 0; mi < 8; mi++) {
      acc[mi][0] = __builtin_amdgcn_mfma_f32_16x16x32_bf16(af[mi], bf0, acc[mi][0], 0, 0, 0);
      acc[mi][1] = __builtin_amdgcn_mfma_f32_16x16x32_bf16(af[mi], bf1, acc[mi][1], 0, 0, 0);
    }
    __builtin_amdgcn_s_setprio(0);
    BAR();

    // ---- phase 3: ks=1, ni={2,3} ----
    bf0 = *(const bf16x8*)(sB + bb * 16384 + 8192 + bBase + 1024);
    bf1 = *(const bf16x8*)(sB + bb * 16384 + 8192 + bBase + 1536);
    if (t + 2 < nt) STAGE_B(bb, 0, kt2);
    BAR();
    __builtin_amdgcn_s_setprio(1);
    #pragma unroll
    for (int mi = 0; mi < 8; mi++) {
      acc[mi][2] = __builtin_amdgcn_mfma_f32_16x16x32_bf16(af[mi], bf0, acc[mi][2], 0, 0, 0);
      acc[mi][3] = __builtin_amdgcn_mfma_f32_16x16x32_bf16(af[mi], bf1, acc[mi][3], 0, 0, 0);
    }
    __builtin_amdgcn_s_setprio(0);
    if (t + 2 < nt)      { WAITV(8); }   // retire A/B-ks0(t+1)
    else if (t + 1 < nt) { WAITV(4); }
    BAR();
  }
  #undef STAGE_A
  #undef STAGE_B

  #pragma unroll
  for (int mi = 0; mi < 8; mi++) {
    const int rb = row0 + wr*128 + mi*16 + quad*4;
    #pragma unroll
    for (int ni = 0; ni < 4; ni++) {
      const int cb = col0 + wc*64 + ni*16 + l16;
      #pragma unroll
      for (int r = 0; r < 4; r++) {
        if (OUT_BF16) ((u16*)Cv)[(size_t)(rb + r) * N + cb] = f2bf(acc[mi][ni][r]);
        else          ((float*)Cv)[(size_t)(rb + r) * N + cb] = acc[mi][ni][r];
      }
    }
  }
}

// ---------------- SwiGLU: ffh = ff * swish(gate) -> amat[:, 2048:] ----------------
__global__ __launch_bounds__(256) void ffh_kernel(const u16* __restrict__ proj,
                                                  u16* __restrict__ amat) {
  const int idx = blockIdx.x * 256 + threadIdx.x;  // 4096*2048 groups of 4
  const int row = idx >> 11;
  const int c = (idx & 2047) * 4;
  const u16* pr = proj + (size_t)row * PLD;
  uint2 fu = *(const uint2*)(pr + 2304 + c);
  uint2 gu = *(const uint2*)(pr + 10496 + c);
  u16 f[4] = {(u16)(fu.x & 0xffffu), (u16)(fu.x >> 16), (u16)(fu.y & 0xffffu), (u16)(fu.y >> 16)};
  u16 g[4] = {(u16)(gu.x & 0xffffu), (u16)(gu.x >> 16), (u16)(gu.y & 0xffffu), (u16)(gu.y >> 16)};
  union { u16 h[4]; uint2 u; } o;
  #pragma unroll
  for (int e = 0; e < 4; e++) {
    float gg = bf2f(g[e]);
    float sw = gg / (1.f + __expf(-gg));
    o.h[e] = f2bf(bf2f(f[e]) * sw);
  }
  *(uint2*)(amat + (size_t)row * ALD + 2048 + c) = o.u;
}

// ---------------- Flash MQA attention -> amat[:, 0:2048] ----------------
__global__ __launch_bounds__(256) void attn_kernel(const u16* __restrict__ proj,
                                                   const float* __restrict__ bias,
                                                   u16* __restrict__ amat) {
  const int it = blockIdx.x, h = blockIdx.y, b = blockIdx.z;
  const int tid = threadIdx.x;
  const int w = tid >> 6, lane = tid & 63, quad = lane >> 4, l16 = lane & 15;
  const int i0 = it * 64;
  __shared__ alignas(16) u16 kt[64*128];   // K tile [j][d]
  __shared__ alignas(16) u16 vt[128*72];   // V^T tile [d][j], stride 72 (16B-aligned rows)
  __shared__ alignas(16) u16 pl[4][16*72]; // per-wave P [q][j], stride 72

  bf16x8 qf[4];
  {
    const u16* qp = proj + (size_t)(b*2048 + i0 + w*16 + l16) * PLD + h*128 + quad*8;
    #pragma unroll
    for (int kst = 0; kst < 4; kst++) qf[kst] = *(const bf16x8*)(qp + kst*32);
  }
  const f32x4 zero = {0.f, 0.f, 0.f, 0.f};
  f32x4 of[8];
  #pragma unroll
  for (int nd = 0; nd < 8; nd++) of[nd] = zero;
  float m_r[4] = {-1e30f, -1e30f, -1e30f, -1e30f};
  float l_r[4] = {0.f, 0.f, 0.f, 0.f};

  for (int j0 = 0; j0 < 2048; j0 += 64) {
    __syncthreads();
    // stage K tile [64][128] via async global->LDS
    #pragma unroll
    for (int i = 0; i < 4; i++) {
      const int segbase = (i*4 + w) * 64;
      const int seg = segbase + lane;
      const int r = seg >> 4, c = (seg & 15) * 8;
      gload_lds16(proj + (size_t)(b*2048 + j0 + r) * PLD + 2048 + c, kt + segbase*8);
    }
    // stage V^T tile (manual transpose, conflict-free stride)
    #pragma unroll
    for (int e = 0; e < 16; e++) {
      const int flat = e*256 + tid;
      const int j = flat >> 6, d2 = (flat & 63) * 2;
      const unsigned int pv = *(const unsigned int*)(proj + (size_t)(b*2048 + j0 + j)*PLD + 2176 + d2);
      vt[d2*72 + j]     = (u16)(pv & 0xffffu);
      vt[(d2+1)*72 + j] = (u16)(pv >> 16);
    }
    __syncthreads();

    // QK^T
    f32x4 sf[4];
    #pragma unroll
    for (int nj = 0; nj < 4; nj++) sf[nj] = zero;
    #pragma unroll
    for (int kst = 0; kst < 4; kst++)
      #pragma unroll
      for (int nj = 0; nj < 4; nj++) {
        bf16x8 bfr = *(const bf16x8*)&kt[(nj*16 + l16)*128 + kst*32 + quad*8];
        sf[nj] = __builtin_amdgcn_mfma_f32_16x16x32_bf16(qf[kst], bfr, sf[nj], 0, 0, 0);
      }

    // scale + bias  (C-layout: row = quad*4+r, col = nj*16+l16)
    const float* bp = bias + ((size_t)h*2048 + (i0 + w*16 + quad*4)) * 2048 + j0 + l16;
    float s[4][4];
    #pragma unroll
    for (int nj = 0; nj < 4; nj++)
      #pragma unroll
      for (int r = 0; r < 4; r++)
        s[nj][r] = sf[nj][r] * QSCALE + bp[(size_t)r*2048 + nj*16];

    // online softmax (row reductions across 16 lanes of each quad)
    float p[4][4]; float alpha[4];
    #pragma unroll
    for (int r = 0; r < 4; r++) {
      float rm = fmaxf(fmaxf(s[0][r], s[1][r]), fmaxf(s[2][r], s[3][r]));
      rm = fmaxf(rm, __shfl_xor(rm, 1, 64));
      rm = fmaxf(rm, __shfl_xor(rm, 2, 64));
      rm = fmaxf(rm, __shfl_xor(rm, 4, 64));
      rm = fmaxf(rm, __shfl_xor(rm, 8, 64));
      const float mn = fmaxf(m_r[r], rm);
      alpha[r] = exp2f((m_r[r] - mn) * LOG2E);
      m_r[r] = mn;
      float rs = 0.f;
      #pragma unroll
      for (int nj = 0; nj < 4; nj++) { p[nj][r] = exp2f((s[nj][r] - mn) * LOG2E); rs += p[nj][r]; }
      rs += __shfl_xor(rs, 1, 64);
      rs += __shfl_xor(rs, 2, 64);
      rs += __shfl_xor(rs, 4, 64);
      rs += __shfl_xor(rs, 8, 64);
      l_r[r] = l_r[r] * alpha[r] + rs;
    }
    #pragma unroll
    for (int nd = 0; nd < 8; nd++)
      #pragma unroll
      for (int r = 0; r < 4; r++) of[nd][r] *= alpha[r];

    // P: C-layout -> LDS (A-layout source)
    #pragma unroll
    for (int nj = 0; nj < 4; nj++)
      #pragma unroll
      for (int r = 0; r < 4; r++)
        pl[w][(quad*4 + r)*72 + nj*16 + l16] = f2bf(p[nj][r]);
    __syncthreads();

    // P @ V
    #pragma unroll
    for (int k2 = 0; k2 < 2; k2++) {
      bf16x8 af = *(const bf16x8*)&pl[w][l16*72 + k2*32 + quad*8];
      #pragma unroll
      for (int nd = 0; nd < 8; nd++) {
        bf16x8 bfr = *(const bf16x8*)&vt[(nd*16 + l16)*72 + k2*32 + quad*8];
        of[nd] = __builtin_amdgcn_mfma_f32_16x16x32_bf16(af, bfr, of[nd], 0, 0, 0);
      }
    }
  }

  const int token = b*2048 + i0 + w*16 + quad*4;
  #pragma unroll
  for (int r = 0; r < 4; r++) {
    const float invl = 1.f / l_r[r];
    u16* op = amat + (size_t)(token + r) * ALD + h*128 + l16;
    #pragma unroll
    for (int nd = 0; nd < 8; nd++) op[nd*16] = f2bf(of[nd][r] * invl);
  }
}

extern "C" void kernel_launch(void* const* d_in, const int* in_sizes, int n_in,
                              void* d_out, int out_size, void* d_ws, size_t ws_size,
                              hipStream_t stream) {
  const float* x       = (const float*)d_in[0];
  const float* bias    = (const float*)d_in[1];
  const float* gamma   = (const float*)d_in[2];
  const float* wi      = (const float*)d_in[3];
  const float* attn_wo = (const float*)d_in[4];
  const float* ff_wo   = (const float*)d_in[5];
  float* out = (float*)d_out;

  char* ws = (char*)d_ws;
  // layout (amat aliases xn+wiT, which are dead after gemm1):
  u16* xn   = (u16*)(ws);                    // 16,777,216 B
  u16* wiT  = (u16*)(ws + 16777216);         // 76,546,048 B  (end 93,323,264)
  u16* amat = (u16*)(ws);                    // 83,886,080 B  (aliases xn+wiT)
  u16* woT  = (u16*)(ws + 93323264);         // 41,943,040 B  (end 135,266,304)
  u16* proj = (u16*)(ws + 135266304);        // 153,092,096 B (end 288,358,400)

  rmsnorm_kernel<<<4096, 256, 0, stream>>>(x, gamma, xn);
  tconv<<<dim3(18688/32, 2048/32), 256, 0, stream>>>(wi, wiT, 2048, 18688, 2048, 0);
  tconv<<<dim3(2048/32, 2048/32), 256, 0, stream>>>(attn_wo, woT, 2048, 2048, 10240, 0);
  tconv<<<dim3(2048/32, 8192/32), 256, 0, stream>>>(ff_wo, woT, 8192, 2048, 10240, 2048);
  // GEMM-1: 256^2 8-phase kernel — 73 col-tiles x 16 row-tiles
  gemm256<1><<<73*16, 512, 0, stream>>>(xn, wiT, proj, 4096, 18688, 2048);
  ffh_kernel<<<32768, 256, 0, stream>>>(proj, amat);
  attn_kernel<<<dim3(32, 16, 2), 256, 0, stream>>>(proj, bias, amat);
  // GEMM-2: 16 col-tiles x 32 row-tiles, single group (GC=16)
  gemm_bt<0, 16><<<16*32, 256, 0, stream>>>(amat, woT, out, 4096, 2048, 10240);
}

// Round 2
// 1458.581 us; speedup vs baseline: 1.1300x; 1.0800x over previous
//
#include <hip/hip_runtime.h>
#include <cstdint>

typedef unsigned short u16;
typedef short bf16x8 __attribute__((ext_vector_type(8)));
typedef float f32x4 __attribute__((ext_vector_type(4)));

#define PLD 18688   // proj leading dim (q2048 | k128 | v128 | ff8192 | gate8192)
#define ALD 10240   // amat leading dim ([attn 2048 | ffh 8192])
#define LOG2E 1.4426950408889634f
#define QSCALE 0.08838834764831845f   // 128^-0.5
#define RMS_SCALE 45.25483399593904f  // 2048^0.5

__device__ __forceinline__ u16 f2bf(float f) {
  union { float f; unsigned int u; } v; v.f = f;
  unsigned int u = v.u;
  return (u16)((u + 0x7fffu + ((u >> 16) & 1u)) >> 16);
}
__device__ __forceinline__ float bf2f(u16 h) {
  union { unsigned int u; float f; } v; v.u = ((unsigned int)h) << 16;
  return v.f;
}

__device__ __forceinline__ void gload_lds16(const void* g, void* l) {
  __builtin_amdgcn_global_load_lds((__attribute__((address_space(1))) void*)(g),
                                   (__attribute__((address_space(3))) void*)(l),
                                   16, 0, 0);
}

// ---------------- RMSNorm: x f32 [4096,2048] -> xn bf16 ----------------
__global__ __launch_bounds__(256) void rmsnorm_kernel(const float* __restrict__ x,
                                                      const float* __restrict__ gamma,
                                                      u16* __restrict__ xn) {
  const int row = blockIdx.x;
  const int tid = threadIdx.x;
  const float4* xr = (const float4*)(x + (size_t)row * 2048);
  float4 v0 = xr[tid], v1 = xr[tid + 256];
  float s = v0.x*v0.x + v0.y*v0.y + v0.z*v0.z + v0.w*v0.w
          + v1.x*v1.x + v1.y*v1.y + v1.z*v1.z + v1.w*v1.w;
  for (int m = 1; m < 64; m <<= 1) s += __shfl_xor(s, m, 64);
  __shared__ float red[4];
  if ((tid & 63) == 0) red[tid >> 6] = s;
  __syncthreads();
  float tot = red[0] + red[1] + red[2] + red[3];
  float inv = rsqrtf(tot + 1e-5f) * RMS_SCALE;
  const float4* gp = (const float4*)gamma;
  float4 g0 = gp[tid], g1 = gp[tid + 256];
  u16* xo = xn + (size_t)row * 2048;
  union { u16 h[4]; uint2 u; } o0, o1;
  o0.h[0] = f2bf(v0.x*inv*g0.x); o0.h[1] = f2bf(v0.y*inv*g0.y);
  o0.h[2] = f2bf(v0.z*inv*g0.z); o0.h[3] = f2bf(v0.w*inv*g0.w);
  o1.h[0] = f2bf(v1.x*inv*g1.x); o1.h[1] = f2bf(v1.y*inv*g1.y);
  o1.h[2] = f2bf(v1.z*inv*g1.z); o1.h[3] = f2bf(v1.w*inv*g1.w);
  *(uint2*)(xo + tid*4) = o0.u;
  *(uint2*)(xo + (tid+256)*4) = o1.u;
}

// ------- transpose+convert: src f32 [K,N] -> dst bf16 [N, dstride] at col doff -------
__global__ __launch_bounds__(256) void tconv(const float* __restrict__ src,
                                             u16* __restrict__ dst,
                                             int K, int N, int dstride, int doff) {
  __shared__ u16 t[32][33];
  const int tx = threadIdx.x & 31, ty = threadIdx.x >> 5;
  const int n0 = blockIdx.x * 32, k0 = blockIdx.y * 32;
  #pragma unroll
  for (int yy = 0; yy < 4; yy++) {
    int r = ty + yy*8;
    t[r][tx] = f2bf(src[(size_t)(k0 + r) * N + n0 + tx]);
  }
  __syncthreads();
  #pragma unroll
  for (int yy = 0; yy < 4; yy++) {
    int r = ty + yy*8;
    dst[(size_t)(n0 + r) * dstride + doff + k0 + tx] = t[tx][r];
  }
}

// ---------------- GEMM (m97 128^2 recipe) — kept for GEMM-2 ----------------
template <int OUT_BF16, int GC>
__global__ __launch_bounds__(256) void gemm_bt(const u16* __restrict__ A,
                                               const u16* __restrict__ Bt,
                                               void* __restrict__ Cv,
                                               int M, int N, int K) {
  __shared__ alignas(16) u16 sA[128*32];
  __shared__ alignas(16) u16 sB[128*32];
  const int numRow = M >> 7;
  const int per = GC * numRow;
  const int pid = blockIdx.x;
  const int g = pid / per, inner = pid % per;
  const int colT = g * GC + inner / numRow;
  const int rowT = inner % numRow;
  const int row0 = rowT * 128, col0 = colT * 128;

  const int tid = threadIdx.x;
  const int w = tid >> 6, lane = tid & 63, quad = lane >> 4, l16 = lane & 15;
  const int wr = (w >> 1) * 64, wc = (w & 1) * 64;
  const f32x4 zero = {0.f, 0.f, 0.f, 0.f};
  f32x4 acc[4][4];
  #pragma unroll
  for (int mi = 0; mi < 4; mi++)
    #pragma unroll
    for (int ni = 0; ni < 4; ni++) acc[mi][ni] = zero;

  for (int k0 = 0; k0 < K; k0 += 32) {
    __syncthreads();
    #pragma unroll
    for (int i = 0; i < 2; i++) {
      const int segbase = (i*4 + w) * 64;
      const int seg = segbase + lane;
      const int r = seg >> 2, c = (seg & 3) * 8;
      gload_lds16(A  + (size_t)(row0 + r) * K + k0 + c, sA + segbase * 8);
      gload_lds16(Bt + (size_t)(col0 + r) * K + k0 + c, sB + segbase * 8);
    }
    __syncthreads();
    bf16x8 af[4], bfr[4];
    #pragma unroll
    for (int mi = 0; mi < 4; mi++)
      af[mi] = *(const bf16x8*)&sA[(wr + mi*16 + l16)*32 + quad*8];
    #pragma unroll
    for (int ni = 0; ni < 4; ni++)
      bfr[ni] = *(const bf16x8*)&sB[(wc + ni*16 + l16)*32 + quad*8];
    #pragma unroll
    for (int mi = 0; mi < 4; mi++)
      #pragma unroll
      for (int ni = 0; ni < 4; ni++)
        acc[mi][ni] = __builtin_amdgcn_mfma_f32_16x16x32_bf16(af[mi], bfr[ni], acc[mi][ni], 0, 0, 0);
  }

  #pragma unroll
  for (int mi = 0; mi < 4; mi++) {
    const int rb = row0 + wr + mi*16 + quad*4;
    #pragma unroll
    for (int ni = 0; ni < 4; ni++) {
      const int cb = col0 + wc + ni*16 + l16;
      #pragma unroll
      for (int r = 0; r < 4; r++) {
        if (OUT_BF16) ((u16*)Cv)[(size_t)(rb + r) * N + cb] = f2bf(acc[mi][ni][r]);
        else          ((float*)Cv)[(size_t)(rb + r) * N + cb] = acc[mi][ni][r];
      }
    }
  }
}

// ---------------- GEMM 256^2 / BK=64 / 8-wave / 8-phase counted-vmcnt ----------------
#define BAR() do { asm volatile("" ::: "memory"); __builtin_amdgcn_s_barrier(); asm volatile("" ::: "memory"); } while (0)
#define WAITV(N) asm volatile("s_waitcnt vmcnt(" #N ")" ::: "memory")

template <int OUT_BF16>
__global__ __launch_bounds__(512, 2) void gemm256(const u16* __restrict__ A,
                                                  const u16* __restrict__ Bt,
                                                  void* __restrict__ Cv,
                                                  int M, int N, int K) {
  __shared__ alignas(16) u16 lds[65536];   // 128 KiB
  u16* const sB = lds + 32768;

  const int numRow = M >> 8;
  int pid = blockIdx.x;
  {  // bijective XCD swizzle (m204 form)
    const int nwg = gridDim.x;
    const int q = nwg >> 3, r = nwg & 7;
    const int xcd = pid & 7, lid = pid >> 3;
    pid = (xcd < r ? xcd * (q + 1) : r * (q + 1) + (xcd - r) * q) + lid;
  }
  const int colT = pid / numRow, rowT = pid % numRow;
  const int row0 = rowT << 8, col0 = colT << 8;

  const int tid = threadIdx.x;
  const int w = tid >> 6, lane = tid & 63, quad = lane >> 4, l16 = lane & 15;
  const int wr = w >> 2, wc = w & 3;           // 2 x 4 wave grid; wave owns 128x64 of C

  const u16* aG  = A  + (size_t)(row0 + w * 16 + l16) * K + quad * 8;
  const u16* aG2 = aG + (size_t)128 * K;
  const u16* bG  = Bt + (size_t)(col0 + w * 16 + l16) * K + quad * 8;
  const u16* bG2 = bG + (size_t)128 * K;

  #define STAGE_A(bb, ks, kt) do { \
    gload_lds16(aG  + (kt) + (ks) * 32, lds + (bb) * 16384 + (ks) * 8192 + w * 512); \
    gload_lds16(aG2 + (kt) + (ks) * 32, lds + (bb) * 16384 + (ks) * 8192 + (8 + w) * 512); \
  } while (0)
  #define STAGE_B(bb, ks, kt) do { \
    gload_lds16(bG  + (kt) + (ks) * 32, sB + (bb) * 16384 + (ks) * 8192 + w * 512); \
    gload_lds16(bG2 + (kt) + (ks) * 32, sB + (bb) * 16384 + (ks) * 8192 + (8 + w) * 512); \
  } while (0)

  const f32x4 zero = {0.f, 0.f, 0.f, 0.f};
  f32x4 acc[8][4];
  #pragma unroll
  for (int mi = 0; mi < 8; mi++)
    #pragma unroll
    for (int ni = 0; ni < 4; ni++) acc[mi][ni] = zero;

  const int nt = K >> 6;
  STAGE_A(0, 0, 0);  STAGE_B(0, 0, 0);
  STAGE_A(0, 1, 0);  STAGE_B(0, 1, 0);
  STAGE_A(1, 0, 64); STAGE_B(1, 0, 64);
  WAITV(8);
  BAR();

  const int aBase = wr * 8 * 512 + lane * 8;
  const int bBase = wc * 4 * 512 + lane * 8;

  for (int t = 0; t < nt; ++t) {
    const int bb = t & 1, nb = bb ^ 1;
    const int kt1 = (t + 1) << 6, kt2 = (t + 2) << 6;
    bf16x8 af[8], bf0, bf1;

    // ---- phase 0: ks=0, ni={0,1} ----
    #pragma unroll
    for (int mi = 0; mi < 8; mi++)
      af[mi] = *(const bf16x8*)(lds + bb * 16384 + aBase + mi * 512);
    bf0 = *(const bf16x8*)(sB + bb * 16384 + bBase);
    bf1 = *(const bf16x8*)(sB + bb * 16384 + bBase + 512);
    if (t + 1 < nt) STAGE_A(nb, 1, kt1);
    BAR();
    __builtin_amdgcn_s_setprio(1);
    #pragma unroll
    for (int mi = 0; mi < 8; mi++) {
      acc[mi][0] = __builtin_amdgcn_mfma_f32_16x16x32_bf16(af[mi], bf0, acc[mi][0], 0, 0, 0);
      acc[mi][1] = __builtin_amdgcn_mfma_f32_16x16x32_bf16(af[mi], bf1, acc[mi][1], 0, 0, 0);
    }
    __builtin_amdgcn_s_setprio(0);
    BAR();

    // ---- phase 1: ks=0, ni={2,3} ----
    bf0 = *(const bf16x8*)(sB + bb * 16384 + bBase + 1024);
    bf1 = *(const bf16x8*)(sB + bb * 16384 + bBase + 1536);
    if (t + 1 < nt) STAGE_B(nb, 1, kt1);
    BAR();
    __builtin_amdgcn_s_setprio(1);
    #pragma unroll
    for (int mi = 0; mi < 8; mi++) {
      acc[mi][2] = __builtin_amdgcn_mfma_f32_16x16x32_bf16(af[mi], bf0, acc[mi][2], 0, 0, 0);
      acc[mi][3] = __builtin_amdgcn_mfma_f32_16x16x32_bf16(af[mi], bf1, acc[mi][3], 0, 0, 0);
    }
    __builtin_amdgcn_s_setprio(0);
    if (t + 1 < nt) { WAITV(8); } else { WAITV(0); }
    BAR();

    // ---- phase 2: ks=1, ni={0,1} ----
    #pragma unroll
    for (int mi = 0; mi < 8; mi++)
      af[mi] = *(const bf16x8*)(lds + bb * 16384 + 8192 + aBase + mi * 512);
    bf0 = *(const bf16x8*)(sB + bb * 16384 + 8192 + bBase);
    bf1 = *(const bf16x8*)(sB + bb * 16384 + 8192 + bBase + 512);
    if (t + 2 < nt) STAGE_A(bb, 0, kt2);
    BAR();
    __builtin_amdgcn_s_setprio(1);
    #pragma unroll
    for (int mi = 0; mi < 8; mi++) {
      acc[mi][0] = __builtin_amdgcn_mfma_f32_16x16x32_bf16(af[mi], bf0, acc[mi][0], 0, 0, 0);
      acc[mi][1] = __builtin_amdgcn_mfma_f32_16x16x32_bf16(af[mi], bf1, acc[mi][1], 0, 0, 0);
    }
    __builtin_amdgcn_s_setprio(0);
    BAR();

    // ---- phase 3: ks=1, ni={2,3} ----
    bf0 = *(const bf16x8*)(sB + bb * 16384 + 8192 + bBase + 1024);
    bf1 = *(const bf16x8*)(sB + bb * 16384 + 8192 + bBase + 1536);
    if (t + 2 < nt) STAGE_B(bb, 0, kt2);
    BAR();
    __builtin_amdgcn_s_setprio(1);
    #pragma unroll
    for (int mi = 0; mi < 8; mi++) {
      acc[mi][2] = __builtin_amdgcn_mfma_f32_16x16x32_bf16(af[mi], bf0, acc[mi][2], 0, 0, 0);
      acc[mi][3] = __builtin_amdgcn_mfma_f32_16x16x32_bf16(af[mi], bf1, acc[mi][3], 0, 0, 0);
    }
    __builtin_amdgcn_s_setprio(0);
    if (t + 2 < nt)      { WAITV(8); }
    else if (t + 1 < nt) { WAITV(4); }
    BAR();
  }
  #undef STAGE_A
  #undef STAGE_B

  #pragma unroll
  for (int mi = 0; mi < 8; mi++) {
    const int rb = row0 + wr*128 + mi*16 + quad*4;
    #pragma unroll
    for (int ni = 0; ni < 4; ni++) {
      const int cb = col0 + wc*64 + ni*16 + l16;
      #pragma unroll
      for (int r = 0; r < 4; r++) {
        if (OUT_BF16) ((u16*)Cv)[(size_t)(rb + r) * N + cb] = f2bf(acc[mi][ni][r]);
        else          ((float*)Cv)[(size_t)(rb + r) * N + cb] = acc[mi][ni][r];
      }
    }
  }
}

// ---------------- SwiGLU: ffh = ff * swish(gate) -> amat[:, 2048:] ----------------
__global__ __launch_bounds__(256) void ffh_kernel(const u16* __restrict__ proj,
                                                  u16* __restrict__ amat) {
  const int idx = blockIdx.x * 256 + threadIdx.x;  // 4096*2048 groups of 4
  const int row = idx >> 11;
  const int c = (idx & 2047) * 4;
  const u16* pr = proj + (size_t)row * PLD;
  uint2 fu = *(const uint2*)(pr + 2304 + c);
  uint2 gu = *(const uint2*)(pr + 10496 + c);
  u16 f[4] = {(u16)(fu.x & 0xffffu), (u16)(fu.x >> 16), (u16)(fu.y & 0xffffu), (u16)(fu.y >> 16)};
  u16 g[4] = {(u16)(gu.x & 0xffffu), (u16)(gu.x >> 16), (u16)(gu.y & 0xffffu), (u16)(gu.y >> 16)};
  union { u16 h[4]; uint2 u; } o;
  #pragma unroll
  for (int e = 0; e < 4; e++) {
    float gg = bf2f(g[e]);
    float sw = gg / (1.f + __expf(-gg));
    o.h[e] = f2bf(bf2f(f[e]) * sw);
  }
  *(uint2*)(amat + (size_t)row * ALD + 2048 + c) = o.u;
}

// ---------------- Flash MQA attention -> amat[:, 0:2048] ----------------
// grid: (32 i-tiles, 16 heads, 2 batch); 4 waves, each owns 16 q-rows.
// LDS swizzle scheme (all tiles): 16B-chunk index within a row is XOR'd with a
// row-derived key so that lanes reading the same column-range of different rows
// land on distinct banks.  kt is staged via global_load_lds (linear LDS dest),
// so the swizzle is applied by permuting the per-lane GLOBAL source chunk
// (rule #21: same involution on source and read side).
__global__ __launch_bounds__(256) void attn_kernel(const u16* __restrict__ proj,
                                                   const float* __restrict__ bias,
                                                   u16* __restrict__ amat) {
  const int it = blockIdx.x, h = blockIdx.y, b = blockIdx.z;
  const int tid = threadIdx.x;
  const int w = tid >> 6, lane = tid & 63, quad = lane >> 4, l16 = lane & 15;
  const int i0 = it * 64;
  __shared__ alignas(16) u16 kt[64*128];   // K tile [j][d], chunk ^= (j&7)
  __shared__ alignas(16) u16 vt[128*64];   // V^T tile [d][j], chunk ^= ((d>>1)&7)
  __shared__ alignas(16) u16 pl[4][16*64]; // per-wave P [q][j], chunk ^= (q&7)

  bf16x8 qf[4];
  {
    const u16* qp = proj + (size_t)(b*2048 + i0 + w*16 + l16) * PLD + h*128 + quad*8;
    #pragma unroll
    for (int kst = 0; kst < 4; kst++) qf[kst] = *(const bf16x8*)(qp + kst*32);
  }
  const f32x4 zero = {0.f, 0.f, 0.f, 0.f};
  f32x4 of[8];
  #pragma unroll
  for (int nd = 0; nd < 8; nd++) of[nd] = zero;
  float m_r[4] = {-1e30f, -1e30f, -1e30f, -1e30f};
  float l_r[4] = {0.f, 0.f, 0.f, 0.f};

  for (int j0 = 0; j0 < 2048; j0 += 64) {
    __syncthreads();
    // stage K tile [64][128] via async global->LDS; LDS linear, source pre-swizzled
    #pragma unroll
    for (int i = 0; i < 4; i++) {
      const int segbase = (i*4 + w) * 64;
      const int seg = segbase + lane;
      const int r = seg >> 4;
      const int c16 = (seg & 15) ^ (r & 7);    // inverse-swizzled source chunk
      gload_lds16(proj + (size_t)(b*2048 + j0 + r) * PLD + 2048 + c16*8, kt + segbase*8);
    }
    // stage V^T tile (manual transpose into swizzled [d][64] layout)
    #pragma unroll
    for (int e = 0; e < 16; e++) {
      const int flat = e*256 + tid;
      const int j = flat >> 6, d2 = (flat & 63) * 2;
      const unsigned int pv = *(const unsigned int*)(proj + (size_t)(b*2048 + j0 + j)*PLD + 2176 + d2);
      const int off = ((((j >> 3) ^ ((d2 >> 1) & 7)) << 3) + (j & 7));
      vt[d2*64 + off]     = (u16)(pv & 0xffffu);
      vt[(d2+1)*64 + off] = (u16)(pv >> 16);
    }
    __syncthreads();

    // QK^T  (kt read: chunk ^= row&7 == l16&7)
    f32x4 sf[4];
    #pragma unroll
    for (int nj = 0; nj < 4; nj++) sf[nj] = zero;
    #pragma unroll
    for (int kst = 0; kst < 4; kst++)
      #pragma unroll
      for (int nj = 0; nj < 4; nj++) {
        bf16x8 bfr = *(const bf16x8*)&kt[(nj*16 + l16)*128 + (((kst*4 + quad) ^ (l16 & 7)))*8];
        sf[nj] = __builtin_amdgcn_mfma_f32_16x16x32_bf16(qf[kst], bfr, sf[nj], 0, 0, 0);
      }

    // scale + bias  (C-layout: row = quad*4+r, col = nj*16+l16)
    const float* bp = bias + ((size_t)h*2048 + (i0 + w*16 + quad*4)) * 2048 + j0 + l16;
    float s[4][4];
    #pragma unroll
    for (int nj = 0; nj < 4; nj++)
      #pragma unroll
      for (int r = 0; r < 4; r++)
        s[nj][r] = sf[nj][r] * QSCALE + bp[(size_t)r*2048 + nj*16];

    // online softmax (row reductions across 16 lanes of each quad)
    float p[4][4]; float alpha[4];
    #pragma unroll
    for (int r = 0; r < 4; r++) {
      float rm = fmaxf(fmaxf(s[0][r], s[1][r]), fmaxf(s[2][r], s[3][r]));
      rm = fmaxf(rm, __shfl_xor(rm, 1, 64));
      rm = fmaxf(rm, __shfl_xor(rm, 2, 64));
      rm = fmaxf(rm, __shfl_xor(rm, 4, 64));
      rm = fmaxf(rm, __shfl_xor(rm, 8, 64));
      const float mn = fmaxf(m_r[r], rm);
      alpha[r] = exp2f((m_r[r] - mn) * LOG2E);
      m_r[r] = mn;
      float rs = 0.f;
      #pragma unroll
      for (int nj = 0; nj < 4; nj++) { p[nj][r] = exp2f((s[nj][r] - mn) * LOG2E); rs += p[nj][r]; }
      rs += __shfl_xor(rs, 1, 64);
      rs += __shfl_xor(rs, 2, 64);
      rs += __shfl_xor(rs, 4, 64);
      rs += __shfl_xor(rs, 8, 64);
      l_r[r] = l_r[r] * alpha[r] + rs;
    }
    #pragma unroll
    for (int nd = 0; nd < 8; nd++)
      #pragma unroll
      for (int r = 0; r < 4; r++) of[nd][r] *= alpha[r];

    // P: C-layout -> LDS (swizzled [q][64])
    #pragma unroll
    for (int nj = 0; nj < 4; nj++)
      #pragma unroll
      for (int r = 0; r < 4; r++) {
        const int q = quad*4 + r;
        pl[w][q*64 + ((((nj*2 + (l16 >> 3)) ^ (q & 7)) << 3) + (l16 & 7))] = f2bf(p[nj][r]);
      }
    __syncthreads();

    // P @ V  (pl read: chunk ^= l16&7;  vt read: chunk ^= (d>>1)&7 == l16>>1)
    #pragma unroll
    for (int k2 = 0; k2 < 2; k2++) {
      bf16x8 af = *(const bf16x8*)&pl[w][l16*64 + (((k2*4 + quad) ^ (l16 & 7)) << 3)];
      #pragma unroll
      for (int nd = 0; nd < 8; nd++) {
        bf16x8 bfr = *(const bf16x8*)&vt[(nd*16 + l16)*64 + (((k2*4 + quad) ^ (l16 >> 1)) << 3)];
        of[nd] = __builtin_amdgcn_mfma_f32_16x16x32_bf16(af, bfr, of[nd], 0, 0, 0);
      }
    }
  }

  const int token = b*2048 + i0 + w*16 + quad*4;
  #pragma unroll
  for (int r = 0; r < 4; r++) {
    const float invl = 1.f / l_r[r];
    u16* op = amat + (size_t)(token + r) * ALD + h*128 + l16;
    #pragma unroll
    for (int nd = 0; nd < 8; nd++) op[nd*16] = f2bf(of[nd][r] * invl);
  }
}

extern "C" void kernel_launch(void* const* d_in, const int* in_sizes, int n_in,
                              void* d_out, int out_size, void* d_ws, size_t ws_size,
                              hipStream_t stream) {
  const float* x       = (const float*)d_in[0];
  const float* bias    = (const float*)d_in[1];
  const float* gamma   = (const float*)d_in[2];
  const float* wi      = (const float*)d_in[3];
  const float* attn_wo = (const float*)d_in[4];
  const float* ff_wo   = (const float*)d_in[5];
  float* out = (float*)d_out;

  char* ws = (char*)d_ws;
  // layout (amat aliases xn+wiT, which are dead after gemm1):
  u16* xn   = (u16*)(ws);                    // 16,777,216 B
  u16* wiT  = (u16*)(ws + 16777216);         // 76,546,048 B  (end 93,323,264)
  u16* amat = (u16*)(ws);                    // 83,886,080 B  (aliases xn+wiT)
  u16* woT  = (u16*)(ws + 93323264);         // 41,943,040 B  (end 135,266,304)
  u16* proj = (u16*)(ws + 135266304);        // 153,092,096 B (end 288,358,400)

  rmsnorm_kernel<<<4096, 256, 0, stream>>>(x, gamma, xn);
  tconv<<<dim3(18688/32, 2048/32), 256, 0, stream>>>(wi, wiT, 2048, 18688, 2048, 0);
  tconv<<<dim3(2048/32, 2048/32), 256, 0, stream>>>(attn_wo, woT, 2048, 2048, 10240, 0);
  tconv<<<dim3(2048/32, 8192/32), 256, 0, stream>>>(ff_wo, woT, 8192, 2048, 10240, 2048);
  // GEMM-1: 256^2 8-phase kernel — 73 col-tiles x 16 row-tiles
  gemm256<1><<<73*16, 512, 0, stream>>>(xn, wiT, proj, 4096, 18688, 2048);
  ffh_kernel<<<32768, 256, 0, stream>>>(proj, amat);
  attn_kernel<<<dim3(32, 16, 2), 256, 0, stream>>>(proj, bias, amat);
  // GEMM-2: 16 col-tiles x 32 row-tiles, single group (GC=16)
  gemm_bt<0, 16><<<16*32, 256, 0, stream>>>(amat, woT, out, 4096, 2048, 10240);
}

// Round 3
// 1458.237 us; speedup vs baseline: 1.1302x; 1.0002x over previous
//
#include <hip/hip_runtime.h>
#include <cstdint>

typedef unsigned short u16;
typedef short bf16x8 __attribute__((ext_vector_type(8)));
typedef float f32x4 __attribute__((ext_vector_type(4)));

#define PLD 18688   // proj leading dim (q2048 | k128 | v128 | ff8192 | gate8192)
#define ALD 10240   // amat leading dim ([attn 2048 | ffh 8192])
#define LOG2E 1.4426950408889634f
#define QSCALE 0.08838834764831845f   // 128^-0.5
#define RMS_SCALE 45.25483399593904f  // 2048^0.5

__device__ __forceinline__ u16 f2bf(float f) {
  union { float f; unsigned int u; } v; v.f = f;
  unsigned int u = v.u;
  return (u16)((u + 0x7fffu + ((u >> 16) & 1u)) >> 16);
}
__device__ __forceinline__ float bf2f(u16 h) {
  union { unsigned int u; float f; } v; v.u = ((unsigned int)h) << 16;
  return v.f;
}

__device__ __forceinline__ void gload_lds16(const void* g, void* l) {
  __builtin_amdgcn_global_load_lds((__attribute__((address_space(1))) void*)(g),
                                   (__attribute__((address_space(3))) void*)(l),
                                   16, 0, 0);
}

// ---------------- RMSNorm: x f32 [4096,2048] -> xn bf16 ----------------
__global__ __launch_bounds__(256) void rmsnorm_kernel(const float* __restrict__ x,
                                                      const float* __restrict__ gamma,
                                                      u16* __restrict__ xn) {
  const int row = blockIdx.x;
  const int tid = threadIdx.x;
  const float4* xr = (const float4*)(x + (size_t)row * 2048);
  float4 v0 = xr[tid], v1 = xr[tid + 256];
  float s = v0.x*v0.x + v0.y*v0.y + v0.z*v0.z + v0.w*v0.w
          + v1.x*v1.x + v1.y*v1.y + v1.z*v1.z + v1.w*v1.w;
  for (int m = 1; m < 64; m <<= 1) s += __shfl_xor(s, m, 64);
  __shared__ float red[4];
  if ((tid & 63) == 0) red[tid >> 6] = s;
  __syncthreads();
  float tot = red[0] + red[1] + red[2] + red[3];
  float inv = rsqrtf(tot + 1e-5f) * RMS_SCALE;
  const float4* gp = (const float4*)gamma;
  float4 g0 = gp[tid], g1 = gp[tid + 256];
  u16* xo = xn + (size_t)row * 2048;
  union { u16 h[4]; uint2 u; } o0, o1;
  o0.h[0] = f2bf(v0.x*inv*g0.x); o0.h[1] = f2bf(v0.y*inv*g0.y);
  o0.h[2] = f2bf(v0.z*inv*g0.z); o0.h[3] = f2bf(v0.w*inv*g0.w);
  o1.h[0] = f2bf(v1.x*inv*g1.x); o1.h[1] = f2bf(v1.y*inv*g1.y);
  o1.h[2] = f2bf(v1.z*inv*g1.z); o1.h[3] = f2bf(v1.w*inv*g1.w);
  *(uint2*)(xo + tid*4) = o0.u;
  *(uint2*)(xo + (tid+256)*4) = o1.u;
}

// ------- transpose+convert: src f32 [K,N] -> dst bf16 [N, dstride] at col doff -------
__global__ __launch_bounds__(256) void tconv(const float* __restrict__ src,
                                             u16* __restrict__ dst,
                                             int K, int N, int dstride, int doff) {
  __shared__ u16 t[32][33];
  const int tx = threadIdx.x & 31, ty = threadIdx.x >> 5;
  const int n0 = blockIdx.x * 32, k0 = blockIdx.y * 32;
  #pragma unroll
  for (int yy = 0; yy < 4; yy++) {
    int r = ty + yy*8;
    t[r][tx] = f2bf(src[(size_t)(k0 + r) * N + n0 + tx]);
  }
  __syncthreads();
  #pragma unroll
  for (int yy = 0; yy < 4; yy++) {
    int r = ty + yy*8;
    dst[(size_t)(n0 + r) * dstride + doff + k0 + tx] = t[tx][r];
  }
}

// ---------------- GEMM (m97 128^2 recipe) — kept for GEMM-2 ----------------
template <int OUT_BF16, int GC>
__global__ __launch_bounds__(256) void gemm_bt(const u16* __restrict__ A,
                                               const u16* __restrict__ Bt,
                                               void* __restrict__ Cv,
                                               int M, int N, int K) {
  __shared__ alignas(16) u16 sA[128*32];
  __shared__ alignas(16) u16 sB[128*32];
  const int numRow = M >> 7;
  const int per = GC * numRow;
  const int pid = blockIdx.x;
  const int g = pid / per, inner = pid % per;
  const int colT = g * GC + inner / numRow;
  const int rowT = inner % numRow;
  const int row0 = rowT * 128, col0 = colT * 128;

  const int tid = threadIdx.x;
  const int w = tid >> 6, lane = tid & 63, quad = lane >> 4, l16 = lane & 15;
  const int wr = (w >> 1) * 64, wc = (w & 1) * 64;
  const f32x4 zero = {0.f, 0.f, 0.f, 0.f};
  f32x4 acc[4][4];
  #pragma unroll
  for (int mi = 0; mi < 4; mi++)
    #pragma unroll
    for (int ni = 0; ni < 4; ni++) acc[mi][ni] = zero;

  for (int k0 = 0; k0 < K; k0 += 32) {
    __syncthreads();
    #pragma unroll
    for (int i = 0; i < 2; i++) {
      const int segbase = (i*4 + w) * 64;
      const int seg = segbase + lane;
      const int r = seg >> 2, c = (seg & 3) * 8;
      gload_lds16(A  + (size_t)(row0 + r) * K + k0 + c, sA + segbase * 8);
      gload_lds16(Bt + (size_t)(col0 + r) * K + k0 + c, sB + segbase * 8);
    }
    __syncthreads();
    bf16x8 af[4], bfr[4];
    #pragma unroll
    for (int mi = 0; mi < 4; mi++)
      af[mi] = *(const bf16x8*)&sA[(wr + mi*16 + l16)*32 + quad*8];
    #pragma unroll
    for (int ni = 0; ni < 4; ni++)
      bfr[ni] = *(const bf16x8*)&sB[(wc + ni*16 + l16)*32 + quad*8];
    #pragma unroll
    for (int mi = 0; mi < 4; mi++)
      #pragma unroll
      for (int ni = 0; ni < 4; ni++)
        acc[mi][ni] = __builtin_amdgcn_mfma_f32_16x16x32_bf16(af[mi], bfr[ni], acc[mi][ni], 0, 0, 0);
  }

  #pragma unroll
  for (int mi = 0; mi < 4; mi++) {
    const int rb = row0 + wr + mi*16 + quad*4;
    #pragma unroll
    for (int ni = 0; ni < 4; ni++) {
      const int cb = col0 + wc + ni*16 + l16;
      #pragma unroll
      for (int r = 0; r < 4; r++) {
        if (OUT_BF16) ((u16*)Cv)[(size_t)(rb + r) * N + cb] = f2bf(acc[mi][ni][r]);
        else          ((float*)Cv)[(size_t)(rb + r) * N + cb] = acc[mi][ni][r];
      }
    }
  }
}

// ---------------- GEMM 256^2 / BK=64 / 8-wave / pipelined 4-phase ----------------
// v2: fragment ds_reads are issued ONE PHASE EARLY (phase k reads phase k+1's
// operands before BAR-a), so the LDS burst drains under barrier + MFMA instead
// of serializing in front of its own MFMA.  Ledger (loads, steady state):
//   stages: P0:A-ks1(t+1)  P1:B-ks1(t+1)  P2:A-ks0(t+2)  P3:B-ks0(t+2)
//   waits:  end-P0 vmcnt(6)  -> retires A/B-ks1(t)   (read at start-P1/P2)
//           end-P2 vmcnt(6)  -> retires A/B-ks0(t+1) (read at start-P3)
//   fresh-region reads always follow (all-waves WAITV) + barrier.
//   stage-write targets verified disjoint from all possibly-pending reads.
#define BAR() do { asm volatile("" ::: "memory"); __builtin_amdgcn_s_barrier(); asm volatile("" ::: "memory"); } while (0)
#define WAITV(N) asm volatile("s_waitcnt vmcnt(" #N ")" ::: "memory")

template <int OUT_BF16>
__global__ __launch_bounds__(512, 2) void gemm256(const u16* __restrict__ A,
                                                  const u16* __restrict__ Bt,
                                                  void* __restrict__ Cv,
                                                  int M, int N, int K) {
  __shared__ alignas(16) u16 lds[65536];   // 128 KiB
  u16* const sB = lds + 32768;

  const int numRow = M >> 8;
  int pid = blockIdx.x;
  {  // bijective XCD swizzle (m204 form)
    const int nwg = gridDim.x;
    const int q = nwg >> 3, r = nwg & 7;
    const int xcd = pid & 7, lid = pid >> 3;
    pid = (xcd < r ? xcd * (q + 1) : r * (q + 1) + (xcd - r) * q) + lid;
  }
  const int colT = pid / numRow, rowT = pid % numRow;
  const int row0 = rowT << 8, col0 = colT << 8;

  const int tid = threadIdx.x;
  const int w = tid >> 6, lane = tid & 63, quad = lane >> 4, l16 = lane & 15;
  const int wr = w >> 2, wc = w & 3;           // 2 x 4 wave grid; wave owns 128x64 of C

  const u16* aG  = A  + (size_t)(row0 + w * 16 + l16) * K + quad * 8;
  const u16* aG2 = aG + (size_t)128 * K;
  const u16* bG  = Bt + (size_t)(col0 + w * 16 + l16) * K + quad * 8;
  const u16* bG2 = bG + (size_t)128 * K;

  #define STAGE_A(bb, ks, kt) do { \
    gload_lds16(aG  + (kt) + (ks) * 32, lds + (bb) * 16384 + (ks) * 8192 + w * 512); \
    gload_lds16(aG2 + (kt) + (ks) * 32, lds + (bb) * 16384 + (ks) * 8192 + (8 + w) * 512); \
  } while (0)
  #define STAGE_B(bb, ks, kt) do { \
    gload_lds16(bG  + (kt) + (ks) * 32, sB + (bb) * 16384 + (ks) * 8192 + w * 512); \
    gload_lds16(bG2 + (kt) + (ks) * 32, sB + (bb) * 16384 + (ks) * 8192 + (8 + w) * 512); \
  } while (0)

  const f32x4 zero = {0.f, 0.f, 0.f, 0.f};
  f32x4 acc[8][4];
  #pragma unroll
  for (int mi = 0; mi < 8; mi++)
    #pragma unroll
    for (int ni = 0; ni < 4; ni++) acc[mi][ni] = zero;

  const int nt = K >> 6;
  const int aBase = wr * 8 * 512 + lane * 8;   // + buf*16384 + ks*8192 + mi*512
  const int bBase = wc * 4 * 512 + lane * 8;   // + buf*16384 + ks*8192 + ni*512

  bf16x8 afX[4], afY[4], bfA[4], bfB[4];

  // prologue: tile0 (8 loads) + tile1 ks0 (4 loads) = 12 in flight
  STAGE_A(0, 0, 0);  STAGE_B(0, 0, 0);
  STAGE_A(0, 1, 0);  STAGE_B(0, 1, 0);
  STAGE_A(1, 0, 64); STAGE_B(1, 0, 64);
  WAITV(8);                      // retire A-ks0(0), B-ks0(0)
  BAR();
  #pragma unroll
  for (int i = 0; i < 4; i++) afX[i] = *(const bf16x8*)(lds + aBase + i * 512);       // ks0 mi0-3
  #pragma unroll
  for (int i = 0; i < 4; i++) bfA[i] = *(const bf16x8*)(sB + bBase + i * 512);        // ks0 ni0-3

  for (int t = 0; t < nt; ++t) {
    const int bb = t & 1, nb = bb ^ 1;
    const int kt1 = (t + 1) << 6, kt2 = (t + 2) << 6;
    const int A0 = bb * 16384 + aBase, A1 = A0 + 8192;
    const int B0 = bb * 16384 + bBase, B1 = B0 + 8192;
    const int nA0 = nb * 16384 + aBase;
    const int nB0 = nb * 16384 + bBase;

    // ---- P0: R:{afY = ks0 mi4-7}  S:A-ks1(t+1)  M: afX x bfA -> acc[0..3]  V:end
    #pragma unroll
    for (int i = 0; i < 4; i++) afY[i] = *(const bf16x8*)(lds + A0 + (4 + i) * 512);
    if (t + 1 < nt) STAGE_A(nb, 1, kt1);
    BAR();
    __builtin_amdgcn_s_setprio(1);
    #pragma unroll
    for (int i = 0; i < 4; i++)
      #pragma unroll
      for (int ni = 0; ni < 4; ni++)
        acc[i][ni] = __builtin_amdgcn_mfma_f32_16x16x32_bf16(afX[i], bfA[ni], acc[i][ni], 0, 0, 0);
    __builtin_amdgcn_s_setprio(0);
    if (t + 1 < nt) { WAITV(6); } else { WAITV(0); }   // retire A/B-ks1(t)
    BAR();

    // ---- P1: R:{afX = ks1 mi0-3, bfB = ks1 ni0-3}  S:B-ks1(t+1)  M: afY x bfA -> acc[4..7]
    #pragma unroll
    for (int i = 0; i < 4; i++) afX[i] = *(const bf16x8*)(lds + A1 + i * 512);
    #pragma unroll
    for (int i = 0; i < 4; i++) bfB[i] = *(const bf16x8*)(sB + B1 + i * 512);
    if (t + 1 < nt) STAGE_B(nb, 1, kt1);
    BAR();
    __builtin_amdgcn_s_setprio(1);
    #pragma unroll
    for (int i = 0; i < 4; i++)
      #pragma unroll
      for (int ni = 0; ni < 4; ni++)
        acc[4 + i][ni] = __builtin_amdgcn_mfma_f32_16x16x32_bf16(afY[i], bfA[ni], acc[4 + i][ni], 0, 0, 0);
    __builtin_amdgcn_s_setprio(0);
    BAR();

    // ---- P2: R:{afY = ks1 mi4-7}  S:A-ks0(t+2)  M: afX x bfB -> acc[0..3]  V:end
    #pragma unroll
    for (int i = 0; i < 4; i++) afY[i] = *(const bf16x8*)(lds + A1 + (4 + i) * 512);
    if (t + 2 < nt) STAGE_A(bb, 0, kt2);
    BAR();
    __builtin_amdgcn_s_setprio(1);
    #pragma unroll
    for (int i = 0; i < 4; i++)
      #pragma unroll
      for (int ni = 0; ni < 4; ni++)
        acc[i][ni] = __builtin_amdgcn_mfma_f32_16x16x32_bf16(afX[i], bfB[ni], acc[i][ni], 0, 0, 0);
    __builtin_amdgcn_s_setprio(0);
    if (t + 2 < nt)      { WAITV(6); }   // retire A/B-ks0(t+1)
    else if (t + 1 < nt) { WAITV(4); }
    BAR();

    // ---- P3: R:{afX = ks0(t+1) mi0-3, bfA = ks0(t+1) ni0-3}  S:B-ks0(t+2)  M: afY x bfB -> acc[4..7]
    if (t + 1 < nt) {
      #pragma unroll
      for (int i = 0; i < 4; i++) afX[i] = *(const bf16x8*)(lds + nA0 + i * 512);
      #pragma unroll
      for (int i = 0; i < 4; i++) bfA[i] = *(const bf16x8*)(sB + nB0 + i * 512);
    }
    if (t + 2 < nt) STAGE_B(bb, 0, kt2);
    BAR();
    __builtin_amdgcn_s_setprio(1);
    #pragma unroll
    for (int i = 0; i < 4; i++)
      #pragma unroll
      for (int ni = 0; ni < 4; ni++)
        acc[4 + i][ni] = __builtin_amdgcn_mfma_f32_16x16x32_bf16(afY[i], bfB[ni], acc[4 + i][ni], 0, 0, 0);
    __builtin_amdgcn_s_setprio(0);
    BAR();
  }
  #undef STAGE_A
  #undef STAGE_B

  #pragma unroll
  for (int mi = 0; mi < 8; mi++) {
    const int rb = row0 + wr*128 + mi*16 + quad*4;
    #pragma unroll
    for (int ni = 0; ni < 4; ni++) {
      const int cb = col0 + wc*64 + ni*16 + l16;
      #pragma unroll
      for (int r = 0; r < 4; r++) {
        if (OUT_BF16) ((u16*)Cv)[(size_t)(rb + r) * N + cb] = f2bf(acc[mi][ni][r]);
        else          ((float*)Cv)[(size_t)(rb + r) * N + cb] = acc[mi][ni][r];
      }
    }
  }
}

// ---------------- SwiGLU: ffh = ff * swish(gate) -> amat[:, 2048:] ----------------
__global__ __launch_bounds__(256) void ffh_kernel(const u16* __restrict__ proj,
                                                  u16* __restrict__ amat) {
  const int idx = blockIdx.x * 256 + threadIdx.x;  // 4096*2048 groups of 4
  const int row = idx >> 11;
  const int c = (idx & 2047) * 4;
  const u16* pr = proj + (size_t)row * PLD;
  uint2 fu = *(const uint2*)(pr + 2304 + c);
  uint2 gu = *(const uint2*)(pr + 10496 + c);
  u16 f[4] = {(u16)(fu.x & 0xffffu), (u16)(fu.x >> 16), (u16)(fu.y & 0xffffu), (u16)(fu.y >> 16)};
  u16 g[4] = {(u16)(gu.x & 0xffffu), (u16)(gu.x >> 16), (u16)(gu.y & 0xffffu), (u16)(gu.y >> 16)};
  union { u16 h[4]; uint2 u; } o;
  #pragma unroll
  for (int e = 0; e < 4; e++) {
    float gg = bf2f(g[e]);
    float sw = gg / (1.f + __expf(-gg));
    o.h[e] = f2bf(bf2f(f[e]) * sw);
  }
  *(uint2*)(amat + (size_t)row * ALD + 2048 + c) = o.u;
}

// ---------------- Flash MQA attention -> amat[:, 0:2048] ----------------
// grid: (32 i-tiles, 16 heads, 2 batch); 4 waves, each owns 16 q-rows.
// LDS swizzle: 16B-chunk index XOR'd with row-derived key (conflict-free reads);
// kt staged via global_load_lds with pre-swizzled per-lane GLOBAL source.
__global__ __launch_bounds__(256) void attn_kernel(const u16* __restrict__ proj,
                                                   const float* __restrict__ bias,
                                                   u16* __restrict__ amat) {
  const int it = blockIdx.x, h = blockIdx.y, b = blockIdx.z;
  const int tid = threadIdx.x;
  const int w = tid >> 6, lane = tid & 63, quad = lane >> 4, l16 = lane & 15;
  const int i0 = it * 64;
  __shared__ alignas(16) u16 kt[64*128];   // K tile [j][d], chunk ^= (j&7)
  __shared__ alignas(16) u16 vt[128*64];   // V^T tile [d][j], chunk ^= ((d>>1)&7)
  __shared__ alignas(16) u16 pl[4][16*64]; // per-wave P [q][j], chunk ^= (q&7)

  bf16x8 qf[4];
  {
    const u16* qp = proj + (size_t)(b*2048 + i0 + w*16 + l16) * PLD + h*128 + quad*8;
    #pragma unroll
    for (int kst = 0; kst < 4; kst++) qf[kst] = *(const bf16x8*)(qp + kst*32);
  }
  const f32x4 zero = {0.f, 0.f, 0.f, 0.f};
  f32x4 of[8];
  #pragma unroll
  for (int nd = 0; nd < 8; nd++) of[nd] = zero;
  float m_r[4] = {-1e30f, -1e30f, -1e30f, -1e30f};
  float l_r[4] = {0.f, 0.f, 0.f, 0.f};

  for (int j0 = 0; j0 < 2048; j0 += 64) {
    __syncthreads();
    // stage K tile [64][128] via async global->LDS; LDS linear, source pre-swizzled
    #pragma unroll
    for (int i = 0; i < 4; i++) {
      const int segbase = (i*4 + w) * 64;
      const int seg = segbase + lane;
      const int r = seg >> 4;
      const int c16 = (seg & 15) ^ (r & 7);    // inverse-swizzled source chunk
      gload_lds16(proj + (size_t)(b*2048 + j0 + r) * PLD + 2048 + c16*8, kt + segbase*8);
    }
    // stage V^T tile (manual transpose into swizzled [d][64] layout)
    #pragma unroll
    for (int e = 0; e < 16; e++) {
      const int flat = e*256 + tid;
      const int j = flat >> 6, d2 = (flat & 63) * 2;
      const unsigned int pv = *(const unsigned int*)(proj + (size_t)(b*2048 + j0 + j)*PLD + 2176 + d2);
      const int off = ((((j >> 3) ^ ((d2 >> 1) & 7)) << 3) + (j & 7));
      vt[d2*64 + off]     = (u16)(pv & 0xffffu);
      vt[(d2+1)*64 + off] = (u16)(pv >> 16);
    }
    __syncthreads();

    // QK^T  (kt read: chunk ^= row&7 == l16&7)
    f32x4 sf[4];
    #pragma unroll
    for (int nj = 0; nj < 4; nj++) sf[nj] = zero;
    #pragma unroll
    for (int kst = 0; kst < 4; kst++)
      #pragma unroll
      for (int nj = 0; nj < 4; nj++) {
        bf16x8 bfr = *(const bf16x8*)&kt[(nj*16 + l16)*128 + (((kst*4 + quad) ^ (l16 & 7)))*8];
        sf[nj] = __builtin_amdgcn_mfma_f32_16x16x32_bf16(qf[kst], bfr, sf[nj], 0, 0, 0);
      }

    // scale + bias  (C-layout: row = quad*4+r, col = nj*16+l16)
    const float* bp = bias + ((size_t)h*2048 + (i0 + w*16 + quad*4)) * 2048 + j0 + l16;
    float s[4][4];
    #pragma unroll
    for (int nj = 0; nj < 4; nj++)
      #pragma unroll
      for (int r = 0; r < 4; r++)
        s[nj][r] = sf[nj][r] * QSCALE + bp[(size_t)r*2048 + nj*16];

    // online softmax (row reductions across 16 lanes of each quad)
    float p[4][4]; float alpha[4];
    #pragma unroll
    for (int r = 0; r < 4; r++) {
      float rm = fmaxf(fmaxf(s[0][r], s[1][r]), fmaxf(s[2][r], s[3][r]));
      rm = fmaxf(rm, __shfl_xor(rm, 1, 64));
      rm = fmaxf(rm, __shfl_xor(rm, 2, 64));
      rm = fmaxf(rm, __shfl_xor(rm, 4, 64));
      rm = fmaxf(rm, __shfl_xor(rm, 8, 64));
      const float mn = fmaxf(m_r[r], rm);
      alpha[r] = exp2f((m_r[r] - mn) * LOG2E);
      m_r[r] = mn;
      float rs = 0.f;
      #pragma unroll
      for (int nj = 0; nj < 4; nj++) { p[nj][r] = exp2f((s[nj][r] - mn) * LOG2E); rs += p[nj][r]; }
      rs += __shfl_xor(rs, 1, 64);
      rs += __shfl_xor(rs, 2, 64);
      rs += __shfl_xor(rs, 4, 64);
      rs += __shfl_xor(rs, 8, 64);
      l_r[r] = l_r[r] * alpha[r] + rs;
    }
    #pragma unroll
    for (int nd = 0; nd < 8; nd++)
      #pragma unroll
      for (int r = 0; r < 4; r++) of[nd][r] *= alpha[r];

    // P: C-layout -> LDS (swizzled [q][64])
    #pragma unroll
    for (int nj = 0; nj < 4; nj++)
      #pragma unroll
      for (int r = 0; r < 4; r++) {
        const int q = quad*4 + r;
        pl[w][q*64 + ((((nj*2 + (l16 >> 3)) ^ (q & 7)) << 3) + (l16 & 7))] = f2bf(p[nj][r]);
      }
    __syncthreads();

    // P @ V  (pl read: chunk ^= l16&7;  vt read: chunk ^= (d>>1)&7 == l16>>1)
    #pragma unroll
    for (int k2 = 0; k2 < 2; k2++) {
      bf16x8 af = *(const bf16x8*)&pl[w][l16*64 + (((k2*4 + quad) ^ (l16 & 7)) << 3)];
      #pragma unroll
      for (int nd = 0; nd < 8; nd++) {
        bf16x8 bfr = *(const bf16x8*)&vt[(nd*16 + l16)*64 + (((k2*4 + quad) ^ (l16 >> 1)) << 3)];
        of[nd] = __builtin_amdgcn_mfma_f32_16x16x32_bf16(af, bfr, of[nd], 0, 0, 0);
      }
    }
  }

  const int token = b*2048 + i0 + w*16 + quad*4;
  #pragma unroll
  for (int r = 0; r < 4; r++) {
    const float invl = 1.f / l_r[r];
    u16* op = amat + (size_t)(token + r) * ALD + h*128 + l16;
    #pragma unroll
    for (int nd = 0; nd < 8; nd++) op[nd*16] = f2bf(of[nd][r] * invl);
  }
}

extern "C" void kernel_launch(void* const* d_in, const int* in_sizes, int n_in,
                              void* d_out, int out_size, void* d_ws, size_t ws_size,
                              hipStream_t stream) {
  const float* x       = (const float*)d_in[0];
  const float* bias    = (const float*)d_in[1];
  const float* gamma   = (const float*)d_in[2];
  const float* wi      = (const float*)d_in[3];
  const float* attn_wo = (const float*)d_in[4];
  const float* ff_wo   = (const float*)d_in[5];
  float* out = (float*)d_out;

  char* ws = (char*)d_ws;
  // layout (amat aliases xn+wiT, which are dead after gemm1):
  u16* xn   = (u16*)(ws);                    // 16,777,216 B
  u16* wiT  = (u16*)(ws + 16777216);         // 76,546,048 B  (end 93,323,264)
  u16* amat = (u16*)(ws);                    // 83,886,080 B  (aliases xn+wiT)
  u16* woT  = (u16*)(ws + 93323264);         // 41,943,040 B  (end 135,266,304)
  u16* proj = (u16*)(ws + 135266304);        // 153,092,096 B (end 288,358,400)

  rmsnorm_kernel<<<4096, 256, 0, stream>>>(x, gamma, xn);
  tconv<<<dim3(18688/32, 2048/32), 256, 0, stream>>>(wi, wiT, 2048, 18688, 2048, 0);
  tconv<<<dim3(2048/32, 2048/32), 256, 0, stream>>>(attn_wo, woT, 2048, 2048, 10240, 0);
  tconv<<<dim3(2048/32, 8192/32), 256, 0, stream>>>(ff_wo, woT, 8192, 2048, 10240, 2048);
  // GEMM-1: 256^2 pipelined 4-phase kernel — 73 col-tiles x 16 row-tiles
  gemm256<1><<<73*16, 512, 0, stream>>>(xn, wiT, proj, 4096, 18688, 2048);
  ffh_kernel<<<32768, 256, 0, stream>>>(proj, amat);
  attn_kernel<<<dim3(32, 16, 2), 256, 0, stream>>>(proj, bias, amat);
  // GEMM-2: 16 col-tiles x 32 row-tiles, single group (GC=16)
  gemm_bt<0, 16><<<16*32, 256, 0, stream>>>(amat, woT, out, 4096, 2048, 10240);
}

// Round 4
// 1454.814 us; speedup vs baseline: 1.1329x; 1.0024x over previous
//
#include <hip/hip_runtime.h>
#include <cstdint>

typedef unsigned short u16;
typedef short bf16x8 __attribute__((ext_vector_type(8)));
typedef float f32x4 __attribute__((ext_vector_type(4)));

#define PLD 18688   // proj leading dim (q2048 | k128 | v128 | ff8192 | gate8192)
#define ALD 10240   // amat leading dim ([attn 2048 | ffh 8192])
#define LOG2E 1.4426950408889634f
#define QSCALE 0.08838834764831845f   // 128^-0.5
#define RMS_SCALE 45.25483399593904f  // 2048^0.5

__device__ __forceinline__ u16 f2bf(float f) {
  union { float f; unsigned int u; } v; v.f = f;
  unsigned int u = v.u;
  return (u16)((u + 0x7fffu + ((u >> 16) & 1u)) >> 16);
}
__device__ __forceinline__ float bf2f(u16 h) {
  union { unsigned int u; float f; } v; v.u = ((unsigned int)h) << 16;
  return v.f;
}

__device__ __forceinline__ void gload_lds16(const void* g, void* l) {
  __builtin_amdgcn_global_load_lds((__attribute__((address_space(1))) void*)(g),
                                   (__attribute__((address_space(3))) void*)(l),
                                   16, 0, 0);
}

// ---------------- RMSNorm: x f32 [4096,2048] -> xn bf16 ----------------
__global__ __launch_bounds__(256) void rmsnorm_kernel(const float* __restrict__ x,
                                                      const float* __restrict__ gamma,
                                                      u16* __restrict__ xn) {
  const int row = blockIdx.x;
  const int tid = threadIdx.x;
  const float4* xr = (const float4*)(x + (size_t)row * 2048);
  float4 v0 = xr[tid], v1 = xr[tid + 256];
  float s = v0.x*v0.x + v0.y*v0.y + v0.z*v0.z + v0.w*v0.w
          + v1.x*v1.x + v1.y*v1.y + v1.z*v1.z + v1.w*v1.w;
  for (int m = 1; m < 64; m <<= 1) s += __shfl_xor(s, m, 64);
  __shared__ float red[4];
  if ((tid & 63) == 0) red[tid >> 6] = s;
  __syncthreads();
  float tot = red[0] + red[1] + red[2] + red[3];
  float inv = rsqrtf(tot + 1e-5f) * RMS_SCALE;
  const float4* gp = (const float4*)gamma;
  float4 g0 = gp[tid], g1 = gp[tid + 256];
  u16* xo = xn + (size_t)row * 2048;
  union { u16 h[4]; uint2 u; } o0, o1;
  o0.h[0] = f2bf(v0.x*inv*g0.x); o0.h[1] = f2bf(v0.y*inv*g0.y);
  o0.h[2] = f2bf(v0.z*inv*g0.z); o0.h[3] = f2bf(v0.w*inv*g0.w);
  o1.h[0] = f2bf(v1.x*inv*g1.x); o1.h[1] = f2bf(v1.y*inv*g1.y);
  o1.h[2] = f2bf(v1.z*inv*g1.z); o1.h[3] = f2bf(v1.w*inv*g1.w);
  *(uint2*)(xo + tid*4) = o0.u;
  *(uint2*)(xo + (tid+256)*4) = o1.u;
}

// ------- transpose+convert: src f32 [K,N] -> dst bf16 [N, dstride] at col doff -------
__global__ __launch_bounds__(256) void tconv(const float* __restrict__ src,
                                             u16* __restrict__ dst,
                                             int K, int N, int dstride, int doff) {
  __shared__ u16 t[32][33];
  const int tx = threadIdx.x & 31, ty = threadIdx.x >> 5;
  const int n0 = blockIdx.x * 32, k0 = blockIdx.y * 32;
  #pragma unroll
  for (int yy = 0; yy < 4; yy++) {
    int r = ty + yy*8;
    t[r][tx] = f2bf(src[(size_t)(k0 + r) * N + n0 + tx]);
  }
  __syncthreads();
  #pragma unroll
  for (int yy = 0; yy < 4; yy++) {
    int r = ty + yy*8;
    dst[(size_t)(n0 + r) * dstride + doff + k0 + tx] = t[tx][r];
  }
}

// ---------------- GEMM (m97 128^2 recipe) — kept for GEMM-2 ----------------
template <int OUT_BF16, int GC>
__global__ __launch_bounds__(256) void gemm_bt(const u16* __restrict__ A,
                                               const u16* __restrict__ Bt,
                                               void* __restrict__ Cv,
                                               int M, int N, int K) {
  __shared__ alignas(16) u16 sA[128*32];
  __shared__ alignas(16) u16 sB[128*32];
  const int numRow = M >> 7;
  const int per = GC * numRow;
  const int pid = blockIdx.x;
  const int g = pid / per, inner = pid % per;
  const int colT = g * GC + inner / numRow;
  const int rowT = inner % numRow;
  const int row0 = rowT * 128, col0 = colT * 128;

  const int tid = threadIdx.x;
  const int w = tid >> 6, lane = tid & 63, quad = lane >> 4, l16 = lane & 15;
  const int wr = (w >> 1) * 64, wc = (w & 1) * 64;
  const f32x4 zero = {0.f, 0.f, 0.f, 0.f};
  f32x4 acc[4][4];
  #pragma unroll
  for (int mi = 0; mi < 4; mi++)
    #pragma unroll
    for (int ni = 0; ni < 4; ni++) acc[mi][ni] = zero;

  for (int k0 = 0; k0 < K; k0 += 32) {
    __syncthreads();
    #pragma unroll
    for (int i = 0; i < 2; i++) {
      const int segbase = (i*4 + w) * 64;
      const int seg = segbase + lane;
      const int r = seg >> 2, c = (seg & 3) * 8;
      gload_lds16(A  + (size_t)(row0 + r) * K + k0 + c, sA + segbase * 8);
      gload_lds16(Bt + (size_t)(col0 + r) * K + k0 + c, sB + segbase * 8);
    }
    __syncthreads();
    bf16x8 af[4], bfr[4];
    #pragma unroll
    for (int mi = 0; mi < 4; mi++)
      af[mi] = *(const bf16x8*)&sA[(wr + mi*16 + l16)*32 + quad*8];
    #pragma unroll
    for (int ni = 0; ni < 4; ni++)
      bfr[ni] = *(const bf16x8*)&sB[(wc + ni*16 + l16)*32 + quad*8];
    #pragma unroll
    for (int mi = 0; mi < 4; mi++)
      #pragma unroll
      for (int ni = 0; ni < 4; ni++)
        acc[mi][ni] = __builtin_amdgcn_mfma_f32_16x16x32_bf16(af[mi], bfr[ni], acc[mi][ni], 0, 0, 0);
  }

  #pragma unroll
  for (int mi = 0; mi < 4; mi++) {
    const int rb = row0 + wr + mi*16 + quad*4;
    #pragma unroll
    for (int ni = 0; ni < 4; ni++) {
      const int cb = col0 + wc + ni*16 + l16;
      #pragma unroll
      for (int r = 0; r < 4; r++) {
        if (OUT_BF16) ((u16*)Cv)[(size_t)(rb + r) * N + cb] = f2bf(acc[mi][ni][r]);
        else          ((float*)Cv)[(size_t)(rb + r) * N + cb] = acc[mi][ni][r];
      }
    }
  }
}

// ---------------- GEMM 256^2 / BK=64 / 8-wave / 4-phase counted-vmcnt (v3) ----------------
// v3: verified m201/m218 sync idiom.  PLAIN s_barrier builtin (no asm memory
// clobbers around it — the R1/R2 BAR() wrapper made the compiler drain
// vmcnt(0) at every barrier, collapsing the counted-vmcnt pipeline).  Each
// phase: {in-phase ds_reads; 1 quarter-stage; s_barrier; lgkmcnt(0)+
// sched_barrier(0) [rule #18]; setprio(1); 16 MFMA; setprio(0); [WAITV];
// s_barrier}.  WAITV keeps its "memory" clobber: it is the fence that stops
// fresh-region LDS reads from hoisting above the staging guard.
// FIFO ledger (2 loads per stage, steady-state queue 8 at tile start):
//   stages: Ph0:A-ks1(t+1)->nb  Ph1:B-ks1(t+1)->nb  Ph2:A-ks0(t+2)->bb  Ph3:B-ks0(t+2)->bb
//   end-Ph1 WAITV(8): retires exactly A/B-ks1(t)   (read at Ph2/Ph3)
//   end-Ph3 WAITV(8): retires exactly A/B-ks0(t+1) (read at next Ph0/Ph1)
//   tails: t=nt-1 end-Ph1 WAITV(0); t=nt-2 end-Ph3 WAITV(4).
//   stage-write regions verified dead at write time (ks0 of bb dead after Ph1).
#define WAITV(N) asm volatile("s_waitcnt vmcnt(" #N ")" ::: "memory")
#define LGKM0()  do { asm volatile("s_waitcnt lgkmcnt(0)"); __builtin_amdgcn_sched_barrier(0); } while (0)

template <int OUT_BF16>
__global__ __launch_bounds__(512, 2) void gemm256(const u16* __restrict__ A,
                                                  const u16* __restrict__ Bt,
                                                  void* __restrict__ Cv,
                                                  int M, int N, int K) {
  __shared__ alignas(16) u16 lds[65536];   // 128 KiB
  u16* const sB = lds + 32768;

  const int numRow = M >> 8;
  int pid = blockIdx.x;
  {  // bijective XCD swizzle (m204 form)
    const int nwg = gridDim.x;
    const int q = nwg >> 3, r = nwg & 7;
    const int xcd = pid & 7, lid = pid >> 3;
    pid = (xcd < r ? xcd * (q + 1) : r * (q + 1) + (xcd - r) * q) + lid;
  }
  const int colT = pid / numRow, rowT = pid % numRow;
  const int row0 = rowT << 8, col0 = colT << 8;

  const int tid = threadIdx.x;
  const int w = tid >> 6, lane = tid & 63, quad = lane >> 4, l16 = lane & 15;
  const int wr = w >> 2, wc = w & 3;           // 2 x 4 wave grid; wave owns 128x64 of C

  const u16* aG  = A  + (size_t)(row0 + w * 16 + l16) * K + quad * 8;
  const u16* aG2 = aG + (size_t)128 * K;
  const u16* bG  = Bt + (size_t)(col0 + w * 16 + l16) * K + quad * 8;
  const u16* bG2 = bG + (size_t)128 * K;

  #define STAGE_A(bb, ks, kt) do { \
    gload_lds16(aG  + (kt) + (ks) * 32, lds + (bb) * 16384 + (ks) * 8192 + w * 512); \
    gload_lds16(aG2 + (kt) + (ks) * 32, lds + (bb) * 16384 + (ks) * 8192 + (8 + w) * 512); \
  } while (0)
  #define STAGE_B(bb, ks, kt) do { \
    gload_lds16(bG  + (kt) + (ks) * 32, sB + (bb) * 16384 + (ks) * 8192 + w * 512); \
    gload_lds16(bG2 + (kt) + (ks) * 32, sB + (bb) * 16384 + (ks) * 8192 + (8 + w) * 512); \
  } while (0)

  const f32x4 zero = {0.f, 0.f, 0.f, 0.f};
  f32x4 acc[8][4];
  #pragma unroll
  for (int mi = 0; mi < 8; mi++)
    #pragma unroll
    for (int ni = 0; ni < 4; ni++) acc[mi][ni] = zero;

  const int nt = K >> 6;
  const int aBase = wr * 8 * 512 + lane * 8;   // + buf*16384 + ks*8192 + mi*512
  const int bBase = wc * 4 * 512 + lane * 8;   // + buf*16384 + ks*8192 + ni*512

  // prologue: queue = 12 loads; WAITV(8) retires A/B-ks0(0)
  STAGE_A(0, 0, 0);  STAGE_B(0, 0, 0);
  STAGE_A(0, 1, 0);  STAGE_B(0, 1, 0);
  STAGE_A(1, 0, 64); STAGE_B(1, 0, 64);
  WAITV(8);
  __builtin_amdgcn_s_barrier();

  for (int t = 0; t < nt; ++t) {
    const int bb = t & 1, nb = bb ^ 1;
    const int kt1 = (t + 1) << 6, kt2 = (t + 2) << 6;
    const int A0 = bb * 16384 + aBase, A1 = A0 + 8192;
    const int B0 = bb * 16384 + bBase, B1 = B0 + 8192;
    bf16x8 af[8], bf0, bf1, bf2, bf3;

    // ---- Ph0: ks0, ni{0,1} ----
    #pragma unroll
    for (int i = 0; i < 8; i++) af[i] = *(const bf16x8*)(lds + A0 + i * 512);
    bf0 = *(const bf16x8*)(sB + B0);
    bf1 = *(const bf16x8*)(sB + B0 + 512);
    if (t + 1 < nt) STAGE_A(nb, 1, kt1);
    __builtin_amdgcn_s_barrier();
    LGKM0();
    __builtin_amdgcn_s_setprio(1);
    #pragma unroll
    for (int i = 0; i < 8; i++) {
      acc[i][0] = __builtin_amdgcn_mfma_f32_16x16x32_bf16(af[i], bf0, acc[i][0], 0, 0, 0);
      acc[i][1] = __builtin_amdgcn_mfma_f32_16x16x32_bf16(af[i], bf1, acc[i][1], 0, 0, 0);
    }
    __builtin_amdgcn_s_setprio(0);
    __builtin_amdgcn_s_barrier();

    // ---- Ph1: ks0, ni{2,3} ----
    bf2 = *(const bf16x8*)(sB + B0 + 1024);
    bf3 = *(const bf16x8*)(sB + B0 + 1536);
    if (t + 1 < nt) STAGE_B(nb, 1, kt1);
    __builtin_amdgcn_s_barrier();
    LGKM0();
    __builtin_amdgcn_s_setprio(1);
    #pragma unroll
    for (int i = 0; i < 8; i++) {
      acc[i][2] = __builtin_amdgcn_mfma_f32_16x16x32_bf16(af[i], bf2, acc[i][2], 0, 0, 0);
      acc[i][3] = __builtin_amdgcn_mfma_f32_16x16x32_bf16(af[i], bf3, acc[i][3], 0, 0, 0);
    }
    __builtin_amdgcn_s_setprio(0);
    if (t + 1 < nt) { WAITV(8); } else { WAITV(0); }   // retire A/B-ks1(t)
    __builtin_amdgcn_s_barrier();

    // ---- Ph2: ks1, ni{0,1} ----
    #pragma unroll
    for (int i = 0; i < 8; i++) af[i] = *(const bf16x8*)(lds + A1 + i * 512);
    bf0 = *(const bf16x8*)(sB + B1);
    bf1 = *(const bf16x8*)(sB + B1 + 512);
    if (t + 2 < nt) STAGE_A(bb, 0, kt2);
    __builtin_amdgcn_s_barrier();
    LGKM0();
    __builtin_amdgcn_s_setprio(1);
    #pragma unroll
    for (int i = 0; i < 8; i++) {
      acc[i][0] = __builtin_amdgcn_mfma_f32_16x16x32_bf16(af[i], bf0, acc[i][0], 0, 0, 0);
      acc[i][1] = __builtin_amdgcn_mfma_f32_16x16x32_bf16(af[i], bf1, acc[i][1], 0, 0, 0);
    }
    __builtin_amdgcn_s_setprio(0);
    __builtin_amdgcn_s_barrier();

    // ---- Ph3: ks1, ni{2,3} ----
    bf2 = *(const bf16x8*)(sB + B1 + 1024);
    bf3 = *(const bf16x8*)(sB + B1 + 1536);
    if (t + 2 < nt) STAGE_B(bb, 0, kt2);
    __builtin_amdgcn_s_barrier();
    LGKM0();
    __builtin_amdgcn_s_setprio(1);
    #pragma unroll
    for (int i = 0; i < 8; i++) {
      acc[i][2] = __builtin_amdgcn_mfma_f32_16x16x32_bf16(af[i], bf2, acc[i][2], 0, 0, 0);
      acc[i][3] = __builtin_amdgcn_mfma_f32_16x16x32_bf16(af[i], bf3, acc[i][3], 0, 0, 0);
    }
    __builtin_amdgcn_s_setprio(0);
    if (t + 2 < nt)      { WAITV(8); }   // retire A/B-ks0(t+1)
    else if (t + 1 < nt) { WAITV(4); }
    __builtin_amdgcn_s_barrier();
  }
  #undef STAGE_A
  #undef STAGE_B

  #pragma unroll
  for (int mi = 0; mi < 8; mi++) {
    const int rb = row0 + wr*128 + mi*16 + quad*4;
    #pragma unroll
    for (int ni = 0; ni < 4; ni++) {
      const int cb = col0 + wc*64 + ni*16 + l16;
      #pragma unroll
      for (int r = 0; r < 4; r++) {
        if (OUT_BF16) ((u16*)Cv)[(size_t)(rb + r) * N + cb] = f2bf(acc[mi][ni][r]);
        else          ((float*)Cv)[(size_t)(rb + r) * N + cb] = acc[mi][ni][r];
      }
    }
  }
}

// ---------------- SwiGLU: ffh = ff * swish(gate) -> amat[:, 2048:] ----------------
__global__ __launch_bounds__(256) void ffh_kernel(const u16* __restrict__ proj,
                                                  u16* __restrict__ amat) {
  const int idx = blockIdx.x * 256 + threadIdx.x;  // 4096*2048 groups of 4
  const int row = idx >> 11;
  const int c = (idx & 2047) * 4;
  const u16* pr = proj + (size_t)row * PLD;
  uint2 fu = *(const uint2*)(pr + 2304 + c);
  uint2 gu = *(const uint2*)(pr + 10496 + c);
  u16 f[4] = {(u16)(fu.x & 0xffffu), (u16)(fu.x >> 16), (u16)(fu.y & 0xffffu), (u16)(fu.y >> 16)};
  u16 g[4] = {(u16)(gu.x & 0xffffu), (u16)(gu.x >> 16), (u16)(gu.y & 0xffffu), (u16)(gu.y >> 16)};
  union { u16 h[4]; uint2 u; } o;
  #pragma unroll
  for (int e = 0; e < 4; e++) {
    float gg = bf2f(g[e]);
    float sw = gg / (1.f + __expf(-gg));
    o.h[e] = f2bf(bf2f(f[e]) * sw);
  }
  *(uint2*)(amat + (size_t)row * ALD + 2048 + c) = o.u;
}

// ---------------- Flash MQA attention -> amat[:, 0:2048] ----------------
// grid: (32 i-tiles, 16 heads, 2 batch); 4 waves, each owns 16 q-rows.
// LDS swizzle: 16B-chunk index XOR'd with row-derived key (conflict-free reads);
// kt staged via global_load_lds with pre-swizzled per-lane GLOBAL source.
__global__ __launch_bounds__(256) void attn_kernel(const u16* __restrict__ proj,
                                                   const float* __restrict__ bias,
                                                   u16* __restrict__ amat) {
  const int it = blockIdx.x, h = blockIdx.y, b = blockIdx.z;
  const int tid = threadIdx.x;
  const int w = tid >> 6, lane = tid & 63, quad = lane >> 4, l16 = lane & 15;
  const int i0 = it * 64;
  __shared__ alignas(16) u16 kt[64*128];   // K tile [j][d], chunk ^= (j&7)
  __shared__ alignas(16) u16 vt[128*64];   // V^T tile [d][j], chunk ^= ((d>>1)&7)
  __shared__ alignas(16) u16 pl[4][16*64]; // per-wave P [q][j], chunk ^= (q&7)

  bf16x8 qf[4];
  {
    const u16* qp = proj + (size_t)(b*2048 + i0 + w*16 + l16) * PLD + h*128 + quad*8;
    #pragma unroll
    for (int kst = 0; kst < 4; kst++) qf[kst] = *(const bf16x8*)(qp + kst*32);
  }
  const f32x4 zero = {0.f, 0.f, 0.f, 0.f};
  f32x4 of[8];
  #pragma unroll
  for (int nd = 0; nd < 8; nd++) of[nd] = zero;
  float m_r[4] = {-1e30f, -1e30f, -1e30f, -1e30f};
  float l_r[4] = {0.f, 0.f, 0.f, 0.f};

  for (int j0 = 0; j0 < 2048; j0 += 64) {
    __syncthreads();
    // stage K tile [64][128] via async global->LDS; LDS linear, source pre-swizzled
    #pragma unroll
    for (int i = 0; i < 4; i++) {
      const int segbase = (i*4 + w) * 64;
      const int seg = segbase + lane;
      const int r = seg >> 4;
      const int c16 = (seg & 15) ^ (r & 7);    // inverse-swizzled source chunk
      gload_lds16(proj + (size_t)(b*2048 + j0 + r) * PLD + 2048 + c16*8, kt + segbase*8);
    }
    // stage V^T tile (manual transpose into swizzled [d][64] layout)
    #pragma unroll
    for (int e = 0; e < 16; e++) {
      const int flat = e*256 + tid;
      const int j = flat >> 6, d2 = (flat & 63) * 2;
      const unsigned int pv = *(const unsigned int*)(proj + (size_t)(b*2048 + j0 + j)*PLD + 2176 + d2);
      const int off = ((((j >> 3) ^ ((d2 >> 1) & 7)) << 3) + (j & 7));
      vt[d2*64 + off]     = (u16)(pv & 0xffffu);
      vt[(d2+1)*64 + off] = (u16)(pv >> 16);
    }
    __syncthreads();

    // QK^T  (kt read: chunk ^= row&7 == l16&7)
    f32x4 sf[4];
    #pragma unroll
    for (int nj = 0; nj < 4; nj++) sf[nj] = zero;
    #pragma unroll
    for (int kst = 0; kst < 4; kst++)
      #pragma unroll
      for (int nj = 0; nj < 4; nj++) {
        bf16x8 bfr = *(const bf16x8*)&kt[(nj*16 + l16)*128 + (((kst*4 + quad) ^ (l16 & 7)))*8];
        sf[nj] = __builtin_amdgcn_mfma_f32_16x16x32_bf16(qf[kst], bfr, sf[nj], 0, 0, 0);
      }

    // scale + bias  (C-layout: row = quad*4+r, col = nj*16+l16)
    const float* bp = bias + ((size_t)h*2048 + (i0 + w*16 + quad*4)) * 2048 + j0 + l16;
    float s[4][4];
    #pragma unroll
    for (int nj = 0; nj < 4; nj++)
      #pragma unroll
      for (int r = 0; r < 4; r++)
        s[nj][r] = sf[nj][r] * QSCALE + bp[(size_t)r*2048 + nj*16];

    // online softmax (row reductions across 16 lanes of each quad)
    float p[4][4]; float alpha[4];
    #pragma unroll
    for (int r = 0; r < 4; r++) {
      float rm = fmaxf(fmaxf(s[0][r], s[1][r]), fmaxf(s[2][r], s[3][r]));
      rm = fmaxf(rm, __shfl_xor(rm, 1, 64));
      rm = fmaxf(rm, __shfl_xor(rm, 2, 64));
      rm = fmaxf(rm, __shfl_xor(rm, 4, 64));
      rm = fmaxf(rm, __shfl_xor(rm, 8, 64));
      const float mn = fmaxf(m_r[r], rm);
      alpha[r] = exp2f((m_r[r] - mn) * LOG2E);
      m_r[r] = mn;
      float rs = 0.f;
      #pragma unroll
      for (int nj = 0; nj < 4; nj++) { p[nj][r] = exp2f((s[nj][r] - mn) * LOG2E); rs += p[nj][r]; }
      rs += __shfl_xor(rs, 1, 64);
      rs += __shfl_xor(rs, 2, 64);
      rs += __shfl_xor(rs, 4, 64);
      rs += __shfl_xor(rs, 8, 64);
      l_r[r] = l_r[r] * alpha[r] + rs;
    }
    #pragma unroll
    for (int nd = 0; nd < 8; nd++)
      #pragma unroll
      for (int r = 0; r < 4; r++) of[nd][r] *= alpha[r];

    // P: C-layout -> LDS (swizzled [q][64])
    #pragma unroll
    for (int nj = 0; nj < 4; nj++)
      #pragma unroll
      for (int r = 0; r < 4; r++) {
        const int q = quad*4 + r;
        pl[w][q*64 + ((((nj*2 + (l16 >> 3)) ^ (q & 7)) << 3) + (l16 & 7))] = f2bf(p[nj][r]);
      }
    __syncthreads();

    // P @ V  (pl read: chunk ^= l16&7;  vt read: chunk ^= (d>>1)&7 == l16>>1)
    #pragma unroll
    for (int k2 = 0; k2 < 2; k2++) {
      bf16x8 af = *(const bf16x8*)&pl[w][l16*64 + (((k2*4 + quad) ^ (l16 & 7)) << 3)];
      #pragma unroll
      for (int nd = 0; nd < 8; nd++) {
        bf16x8 bfr = *(const bf16x8*)&vt[(nd*16 + l16)*64 + (((k2*4 + quad) ^ (l16 >> 1)) << 3)];
        of[nd] = __builtin_amdgcn_mfma_f32_16x16x32_bf16(af, bfr, of[nd], 0, 0, 0);
      }
    }
  }

  const int token = b*2048 + i0 + w*16 + quad*4;
  #pragma unroll
  for (int r = 0; r < 4; r++) {
    const float invl = 1.f / l_r[r];
    u16* op = amat + (size_t)(token + r) * ALD + h*128 + l16;
    #pragma unroll
    for (int nd = 0; nd < 8; nd++) op[nd*16] = f2bf(of[nd][r] * invl);
  }
}

extern "C" void kernel_launch(void* const* d_in, const int* in_sizes, int n_in,
                              void* d_out, int out_size, void* d_ws, size_t ws_size,
                              hipStream_t stream) {
  const float* x       = (const float*)d_in[0];
  const float* bias    = (const float*)d_in[1];
  const float* gamma   = (const float*)d_in[2];
  const float* wi      = (const float*)d_in[3];
  const float* attn_wo = (const float*)d_in[4];
  const float* ff_wo   = (const float*)d_in[5];
  float* out = (float*)d_out;

  char* ws = (char*)d_ws;
  // layout (amat aliases xn+wiT, which are dead after gemm1):
  u16* xn   = (u16*)(ws);                    // 16,777,216 B
  u16* wiT  = (u16*)(ws + 16777216);         // 76,546,048 B  (end 93,323,264)
  u16* amat = (u16*)(ws);                    // 83,886,080 B  (aliases xn+wiT)
  u16* woT  = (u16*)(ws + 93323264);         // 41,943,040 B  (end 135,266,304)
  u16* proj = (u16*)(ws + 135266304);        // 153,092,096 B (end 288,358,400)

  rmsnorm_kernel<<<4096, 256, 0, stream>>>(x, gamma, xn);
  tconv<<<dim3(18688/32, 2048/32), 256, 0, stream>>>(wi, wiT, 2048, 18688, 2048, 0);
  tconv<<<dim3(2048/32, 2048/32), 256, 0, stream>>>(attn_wo, woT, 2048, 2048, 10240, 0);
  tconv<<<dim3(2048/32, 8192/32), 256, 0, stream>>>(ff_wo, woT, 8192, 2048, 10240, 2048);
  // GEMM-1: 256^2 4-phase counted-vmcnt kernel — 73 col-tiles x 16 row-tiles
  gemm256<1><<<73*16, 512, 0, stream>>>(xn, wiT, proj, 4096, 18688, 2048);
  ffh_kernel<<<32768, 256, 0, stream>>>(proj, amat);
  attn_kernel<<<dim3(32, 16, 2), 256, 0, stream>>>(proj, bias, amat);
  // GEMM-2: 16 col-tiles x 32 row-tiles, single group (GC=16)
  gemm_bt<0, 16><<<16*32, 256, 0, stream>>>(amat, woT, out, 4096, 2048, 10240);
}